// Round 13
// baseline (748.326 us; speedup 1.0000x reference)
//
#include <hip/hip_runtime.h>

#define N_NODES 50000
#define N_EDGES 800000
#define N_GRAPHS 256
#define F_IN 9
#define GF_DIM 187
#define HO1 256
#define HO2 512
#define FC1_DIM 128
#define Z_DIM (HO2 + GF_DIM)   // 699

// ---------------- workspace layout (bytes) — proven footprint ----------------
#define OFF_XL1   0UL
#define OFF_XR1   25600000UL
#define OFF_XLR2  0UL
#define OFF_H1    102400000UL
#define OFF_H2    102400000UL
#define OFF_SMALL 153600000UL
#define OFF_DEG    (OFF_SMALL + 0UL)
#define OFF_ROWPTR (OFF_SMALL + 200704UL)
#define OFF_CURSOR (OFF_SMALL + 401408UL)
#define OFF_COL    (OFF_SMALL + 602112UL)
#define OFF_GS     (OFF_SMALL + 3802112UL)
#define OFF_POOLED (OFF_SMALL + 3806208UL)   // 512 KB fp32 pooled
#define OFF_WCAT   (OFF_SMALL + 4330496UL)
#define OFF_BCAT   (OFF_SMALL + 5379072UL)
#define WS_REQUIRED (OFF_SMALL + 5383168UL)   // 158,983,168 (proven)

typedef _Float16 half_t;
typedef __attribute__((ext_vector_type(2))) _Float16 h2;
typedef __attribute__((ext_vector_type(8))) _Float16 half8;   // f16 MFMA frag
typedef __attribute__((ext_vector_type(4))) float floatx4;

__device__ __forceinline__ h2 h2_bc(unsigned u) { return __builtin_bit_cast(h2, u); }
__device__ __forceinline__ unsigned u_bc(h2 v) { return __builtin_bit_cast(unsigned, v); }

// packed logit step over 4 words (8 halves): q += a06.(xs+xr) + a04.|xs+xr|
__device__ __forceinline__ float edge_logit_h(const unsigned* w, const h2* xr2,
                                              const h2* a06, const h2* a04,
                                              h2* xv2) {
    float q = 0.f;
#pragma unroll
    for (int i = 0; i < 4; ++i) {
        h2 xs = h2_bc(w[i]);
        xv2[i] = xs;
        h2 v = xs + xr2[i];                       // v_pk_add_f16
        q = __builtin_amdgcn_fdot2(a06[i], v, q, false);
        h2 va = h2_bc(u_bc(v) & 0x7fff7fffu);     // packed abs
        q = __builtin_amdgcn_fdot2(a04[i], va, q, false);
    }
    return q;
}

// ---------------- diagnostic fallback (ws too small) ----------------
__global__ void diag_kernel(float* out, float v) { out[threadIdx.x] = v; }

// ---------------- fused setup: zero deg | graph starts | pack W2 ----------------
__global__ __launch_bounds__(256) void setup_kernel(int* __restrict__ deg,
                                                    const int* __restrict__ batch,
                                                    int* __restrict__ gs,
                                                    const float* __restrict__ Wl2,
                                                    const float* __restrict__ Wr2,
                                                    const float* __restrict__ bl2,
                                                    const float* __restrict__ br2,
                                                    half_t* __restrict__ Wt,
                                                    float* __restrict__ bcat) {
    const int b = blockIdx.x, t = threadIdx.x;
    if (b < 196) {
        int i = b * 256 + t;
        if (i < N_NODES) deg[i] = 0;
    } else if (b == 196) {
        int lo = 0, hi = N_NODES;
        while (lo < hi) {
            int mid = (lo + hi) >> 1;
            if (batch[mid] < t) lo = mid + 1; else hi = mid;
        }
        gs[t] = lo;
        if (t == 0) gs[N_GRAPHS] = N_NODES;
    } else {
        int i = (b - 197) * 256 + t;          // 0 .. 1024*256-1
        int n = i >> 8, k = i & 255;
        float w = (n < HO2) ? Wl2[k * HO2 + n] : Wr2[k * HO2 + (n - HO2)];
        Wt[i] = (half_t)w;
        if (i < 1024) bcat[i] = (i < HO2) ? bl2[i] : br2[i - HO2];
    }
}

// ---------------- CSR build ----------------
__global__ __launch_bounds__(256) void count_kernel(const int* __restrict__ ei,
                                                    int* __restrict__ deg) {
    int e = blockIdx.x * 256 + threadIdx.x;
    if (e < N_EDGES) atomicAdd(&deg[ei[N_EDGES + e]], 1);
}

__global__ __launch_bounds__(1024) void scan_kernel(const int* __restrict__ deg,
                                                    int* __restrict__ rowptr,
                                                    int* __restrict__ cursor) {
    __shared__ int part[1024];
    const int t = threadIdx.x;
    const int CH = (N_NODES + 1023) / 1024;   // 49
    int lo = t * CH;
    int hi = lo + CH; if (hi > N_NODES) hi = N_NODES;
    int s = 0;
    for (int i = lo; i < hi; ++i) s += deg[i];
    part[t] = s;
    __syncthreads();
    for (int off = 1; off < 1024; off <<= 1) {
        int v = (t >= off) ? part[t - off] : 0;
        __syncthreads();
        part[t] += v;
        __syncthreads();
    }
    int run = part[t] - s;  // exclusive base
    for (int i = lo; i < hi; ++i) {
        int d = deg[i];
        rowptr[i] = run;
        cursor[i] = run;
        run += d;
    }
    if (t == 1023) rowptr[N_NODES] = part[1023];
}

__global__ __launch_bounds__(256) void fill_kernel(const int* __restrict__ ei,
                                                   int* __restrict__ cursor,
                                                   int* __restrict__ col) {
    int e = blockIdx.x * 256 + threadIdx.x;
    if (e < N_EDGES) {
        int d = ei[N_EDGES + e];
        int pos = atomicAdd(&cursor[d], 1);
        col[pos] = ei[e];
    }
}

// ---------------- layer-1 linear (K=9), 8 nodes/block, fp16 out ----------------
__global__ __launch_bounds__(256) void mm1_kernel(const float* __restrict__ x,
                                                  const float* __restrict__ Wl,
                                                  const float* __restrict__ bl,
                                                  const float* __restrict__ Wr,
                                                  const float* __restrict__ br,
                                                  half_t* __restrict__ xl,
                                                  half_t* __restrict__ xr) {
    __shared__ float xs[8][F_IN];
    const int n0 = blockIdx.x * 8;           // N_NODES divisible by 8
    const int t = threadIdx.x;
    if (t < 8 * F_IN) xs[t / F_IN][t % F_IN] = x[n0 * F_IN + t];
    __syncthreads();
    const float blv = bl[t], brv = br[t];
    float sl[8], sr[8];
#pragma unroll
    for (int i = 0; i < 8; ++i) { sl[i] = blv; sr[i] = brv; }
#pragma unroll
    for (int k = 0; k < F_IN; ++k) {
        float wlk = Wl[k * HO1 + t];
        float wrk = Wr[k * HO1 + t];
#pragma unroll
        for (int i = 0; i < 8; ++i) {
            sl[i] = fmaf(xs[i][k], wlk, sl[i]);
            sr[i] = fmaf(xs[i][k], wrk, sr[i]);
        }
    }
#pragma unroll
    for (int i = 0; i < 8; ++i) {
        xl[(size_t)(n0 + i) * HO1 + t] = (half_t)sl[i];
        xr[(size_t)(n0 + i) * HO1 + t] = (half_t)sr[i];
    }
}

// ---------------- layer-2 linear: f16 MFMA, double-buffered LDS pipeline ----------------
#define LP 40
__global__ __launch_bounds__(256) void mm2_mfma_kernel(
    const half_t* __restrict__ A,    // h1 fp16 [N,256]
    const half_t* __restrict__ Bt,   // Wt fp16 [1024][256]
    const float* __restrict__ bias,  // bcat [1024]
    half_t* __restrict__ C) {        // xlr2 fp16 [N,1024]
    __shared__ half_t As[2][128 * LP];  // 2 x 10 KB
    __shared__ half_t Bs[2][128 * LP];  // 2 x 10 KB
    const int t = threadIdx.x;
    const int lane = t & 63;
    const int w = t >> 6;
    const int wr = w >> 1, wc = w & 1;       // wave quadrant (64x64)
    const int l15 = lane & 15, kq = lane >> 4;
    const int row0 = blockIdx.y * 128;
    const int col0 = blockIdx.x * 128;

    const int c1 = t, c2 = t + 256;
    int ar1 = row0 + (c1 >> 2); ar1 = ar1 < N_NODES ? ar1 : N_NODES - 1;
    int ar2 = row0 + (c2 >> 2); ar2 = ar2 < N_NODES ? ar2 : N_NODES - 1;
    const half_t* pa1 = A + (size_t)ar1 * 256 + (c1 & 3) * 8;
    const half_t* pa2 = A + (size_t)ar2 * 256 + (c2 & 3) * 8;
    const half_t* pb1 = Bt + (size_t)(col0 + (c1 >> 2)) * 256 + (c1 & 3) * 8;
    const half_t* pb2 = Bt + (size_t)(col0 + (c2 >> 2)) * 256 + (c2 & 3) * 8;
    const int la1 = (c1 >> 2) * LP + (c1 & 3) * 8;
    const int la2 = (c2 >> 2) * LP + (c2 & 3) * 8;

    uint4 va1, va2, vb1, vb2;
    va1 = *(const uint4*)(pa1);  va2 = *(const uint4*)(pa2);
    vb1 = *(const uint4*)(pb1);  vb2 = *(const uint4*)(pb2);
    *(uint4*)&As[0][la1] = va1;  *(uint4*)&As[0][la2] = va2;
    *(uint4*)&Bs[0][la1] = vb1;  *(uint4*)&Bs[0][la2] = vb2;

    floatx4 acc[4][4] = {};
    int buf = 0;
    for (int k0 = 0; k0 < 256; k0 += 32) {
        __syncthreads();
        const bool more = (k0 + 32 < 256);
        if (more) {
            va1 = *(const uint4*)(pa1 + k0 + 32);
            va2 = *(const uint4*)(pa2 + k0 + 32);
            vb1 = *(const uint4*)(pb1 + k0 + 32);
            vb2 = *(const uint4*)(pb2 + k0 + 32);
        }
        half8 af[4], bf[4];
#pragma unroll
        for (int i = 0; i < 4; ++i)
            af[i] = *(const half8*)&As[buf][(wr * 64 + i * 16 + l15) * LP + kq * 8];
#pragma unroll
        for (int j = 0; j < 4; ++j)
            bf[j] = *(const half8*)&Bs[buf][(wc * 64 + j * 16 + l15) * LP + kq * 8];
#pragma unroll
        for (int i = 0; i < 4; ++i)
#pragma unroll
            for (int j = 0; j < 4; ++j)
                acc[i][j] = __builtin_amdgcn_mfma_f32_16x16x32_f16(
                    af[i], bf[j], acc[i][j], 0, 0, 0);
        if (more) {
            int nb = 1 - buf;
            *(uint4*)&As[nb][la1] = va1;  *(uint4*)&As[nb][la2] = va2;
            *(uint4*)&Bs[nb][la1] = vb1;  *(uint4*)&Bs[nb][la2] = vb2;
            buf = nb;
        }
    }
#pragma unroll
    for (int j = 0; j < 4; ++j) {
        int col = col0 + wc * 64 + j * 16 + l15;
        float bj = bias[col];
#pragma unroll
        for (int i = 0; i < 4; ++i) {
            int rbase = row0 + wr * 64 + i * 16 + kq * 4;
            floatx4 v = acc[i][j];
#pragma unroll
            for (int r = 0; r < 4; ++r) {
                int row = rbase + r;
                if (row < N_NODES) C[(size_t)row * 1024 + col] = (half_t)(v[r] + bj);
            }
        }
    }
}

// ---------------- gat1: GROUPS=2 lane-split, packed fp16 math ----------------
template <int O, int GROUPS>
__global__ __launch_bounds__(256, 4) void gat_node_kernel(
    const half_t* __restrict__ xl_, const half_t* __restrict__ xr_,
    int stride,
    const int* __restrict__ rowptr, const int* __restrict__ col,
    const float* __restrict__ att, const float* __restrict__ bias,
    const float* __restrict__ bng, const float* __restrict__ bnb,
    const float* __restrict__ bnm, const float* __restrict__ bnv,
    half_t* __restrict__ out_) {
    constexpr int TOT = 4 * O;
    constexpr int GS  = 64 / GROUPS;
    constexpr int VE  = TOT / GS;     // 8
    constexpr int LPH = O / VE;
    const int wave = threadIdx.x >> 6;
    const int node = blockIdx.x * 4 + wave;
    if (node >= N_NODES) return;
    const int lane = threadIdx.x & 63;
    const int gid  = lane / GS;
    const int gl   = lane % GS;
    const int cbase = gl * VE;

    h2 xr2[4], a06[4], a04[4], acc2[4], xvA[4], xvB[4];
    {
        uint4 q = *(const uint4*)(xr_ + (size_t)node * stride + cbase);
        xr2[0] = h2_bc(q.x); xr2[1] = h2_bc(q.y);
        xr2[2] = h2_bc(q.z); xr2[3] = h2_bc(q.w);
#pragma unroll
        for (int v = 0; v < VE; v += 4) {
            float4 b = *(const float4*)(att + cbase + v);
            a06[v / 2]     = h2{(half_t)(0.6f * b.x), (half_t)(0.6f * b.y)};
            a06[v / 2 + 1] = h2{(half_t)(0.6f * b.z), (half_t)(0.6f * b.w)};
            a04[v / 2]     = h2{(half_t)(0.4f * b.x), (half_t)(0.4f * b.y)};
            a04[v / 2 + 1] = h2{(half_t)(0.4f * b.z), (half_t)(0.4f * b.w)};
        }
    }
    float s;
    {
        unsigned w_[4];
        *(uint4*)w_ = *(const uint4*)(xl_ + (size_t)node * stride + cbase);
        float q = edge_logit_h(w_, xr2, a06, a04, xvA);
#pragma unroll
        for (int d = 1; d < LPH; d <<= 1) q += __shfl_xor(q, d, 64);
        float w0 = (GROUPS == 1 || gid == 0) ? __expf(q) : 0.f;
        s = w0;
        h2 w0h = h2{(half_t)w0, (half_t)w0};
#pragma unroll
        for (int j = 0; j < 4; ++j) acc2[j] = w0h * xvA[j];
    }

    const int e0 = rowptr[node], e1 = rowptr[node + 1];
    const int deg = e1 - e0;
    constexpr int PER = 2 * GROUPS;
    const int itc = (deg + PER - 1) / PER;
    const int elast = e1 - 1;
    int ia = e0 + 2 * gid;
    unsigned nA[4], nB[4];
    if (itc > 0) {
        int a = ia < elast ? ia : elast;
        int b = ia + 1 < elast ? ia + 1 : elast;
        *(uint4*)nA = *(const uint4*)(xl_ + (size_t)col[a] * stride + cbase);
        *(uint4*)nB = *(const uint4*)(xl_ + (size_t)col[b] * stride + cbase);
    }
    for (int k = 0; k < itc; ++k) {
        unsigned cA[4], cB[4];
#pragma unroll
        for (int i = 0; i < 4; ++i) { cA[i] = nA[i]; cB[i] = nB[i]; }
        int inext = ia + PER;
        if (k + 1 < itc) {
            int a = inext < elast ? inext : elast;
            int b = inext + 1 < elast ? inext + 1 : elast;
            *(uint4*)nA = *(const uint4*)(xl_ + (size_t)col[a] * stride + cbase);
            *(uint4*)nB = *(const uint4*)(xl_ + (size_t)col[b] * stride + cbase);
        }
        float q1 = edge_logit_h(cA, xr2, a06, a04, xvA);
        float q2 = edge_logit_h(cB, xr2, a06, a04, xvB);
#pragma unroll
        for (int d = 1; d < LPH; d <<= 1) {
            q1 += __shfl_xor(q1, d, 64);
            q2 += __shfl_xor(q2, d, 64);
        }
        float w1 = (ia < e1) ? __expf(q1) : 0.f;
        float w2 = (ia + 1 < e1) ? __expf(q2) : 0.f;
        s += w1 + w2;
        h2 w1h = h2{(half_t)w1, (half_t)w1};
        h2 w2h = h2{(half_t)w2, (half_t)w2};
#pragma unroll
        for (int j = 0; j < 4; ++j)
            acc2[j] += w1h * xvA[j] + w2h * xvB[j];
        ia = inext;
    }
    if constexpr (GROUPS == 2) {
        s += __shfl_xor(s, 32, 64);
#pragma unroll
        for (int j = 0; j < 4; ++j) {
            float tmp = __builtin_bit_cast(float, acc2[j]);
            float o = __shfl_xor(tmp, 32, 64);
            acc2[j] += __builtin_bit_cast(h2, o);
        }
    }
    float r = 1.f / (s + 1e-16f);
    if (GROUPS == 1 || gid == 0) {
        half_t t[8];
#pragma unroll
        for (int j = 0; j < 4; ++j) {
#pragma unroll
            for (int p = 0; p < 2; ++p) {
                int c = cbase + 2 * j + p;
                float val = (float)acc2[j][p] * r + bias[c];
                float y = bng[c] * (val - bnm[c]) * rsqrtf(bnv[c] + 1e-5f) + bnb[c];
                t[2 * j + p] = (half_t)fmaxf(y, 0.f);
            }
        }
        uint4 qo;
        qo.x = u_bc(h2{t[0], t[1]});
        qo.y = u_bc(h2{t[2], t[3]});
        qo.z = u_bc(h2{t[4], t[5]});
        qo.w = u_bc(h2{t[6], t[7]});
        *(uint4*)(out_ + (size_t)node * TOT + cbase) = qo;
    }
}

// ---------------- gat2: r8-exact loop shape, packed fp16 math ----------------
template <int O>
__global__ __launch_bounds__(256, 4) void gat2_kernel(
    const half_t* __restrict__ xl_, const half_t* __restrict__ xr_,
    int stride,
    const int* __restrict__ rowptr, const int* __restrict__ col,
    const float* __restrict__ att, const float* __restrict__ bias,
    const float* __restrict__ bng, const float* __restrict__ bnb,
    const float* __restrict__ bnm, const float* __restrict__ bnv,
    half_t* __restrict__ out_) {
    constexpr int VE = O / 16;        // 8
    constexpr int HO = 4 * O;
    const int wave = threadIdx.x >> 6;
    const int node = blockIdx.x * 4 + wave;
    if (node >= N_NODES) return;
    const int lane = threadIdx.x & 63;
    const int l16 = lane & 15;
    const int cbase = (lane >> 4) * O + l16 * VE;

    h2 xr2[4], a06[4], a04[4], acc2[4], xvA[4], xvB[4];
    {
        uint4 q = *(const uint4*)(xr_ + (size_t)node * stride + cbase);
        xr2[0] = h2_bc(q.x); xr2[1] = h2_bc(q.y);
        xr2[2] = h2_bc(q.z); xr2[3] = h2_bc(q.w);
#pragma unroll
        for (int v = 0; v < VE; v += 4) {
            float4 b = *(const float4*)(att + cbase + v);
            a06[v / 2]     = h2{(half_t)(0.6f * b.x), (half_t)(0.6f * b.y)};
            a06[v / 2 + 1] = h2{(half_t)(0.6f * b.z), (half_t)(0.6f * b.w)};
            a04[v / 2]     = h2{(half_t)(0.4f * b.x), (half_t)(0.4f * b.y)};
            a04[v / 2 + 1] = h2{(half_t)(0.4f * b.z), (half_t)(0.4f * b.w)};
        }
    }
    float s;
    {
        unsigned ws_[4];
        *(uint4*)ws_ = *(const uint4*)(xl_ + (size_t)node * stride + cbase);
        float q = edge_logit_h(ws_, xr2, a06, a04, xvA);
#pragma unroll
        for (int d = 1; d < 16; d <<= 1) q += __shfl_xor(q, d, 64);
        float w0 = __expf(q);
        s = w0;
        h2 w0h = h2{(half_t)w0, (half_t)w0};
#pragma unroll
        for (int j = 0; j < 4; ++j) acc2[j] = w0h * xvA[j];
    }

    int e = rowptr[node];
    const int e1 = rowptr[node + 1];
    const int elast = e1 - 1;
    unsigned nA[4], nB[4];
    if (e < e1) *(uint4*)nA = *(const uint4*)(xl_ + (size_t)col[e] * stride + cbase);
    if (e + 1 < e1) *(uint4*)nB = *(const uint4*)(xl_ + (size_t)col[e + 1] * stride + cbase);
    while (e + 1 < e1) {
        unsigned cA[4], cB[4];
#pragma unroll
        for (int i = 0; i < 4; ++i) { cA[i] = nA[i]; cB[i] = nB[i]; }
        int i2 = e + 2 < elast ? e + 2 : elast;
        int i3 = e + 3 < elast ? e + 3 : elast;
        *(uint4*)nA = *(const uint4*)(xl_ + (size_t)col[i2] * stride + cbase);
        *(uint4*)nB = *(const uint4*)(xl_ + (size_t)col[i3] * stride + cbase);
        e += 2;
        float q1 = edge_logit_h(cA, xr2, a06, a04, xvA);
        float q2 = edge_logit_h(cB, xr2, a06, a04, xvB);
#pragma unroll
        for (int d = 1; d < 16; d <<= 1) {
            q1 += __shfl_xor(q1, d, 64);
            q2 += __shfl_xor(q2, d, 64);
        }
        float w1 = __expf(q1), w2 = __expf(q2);
        s += w1 + w2;
        h2 w1h = h2{(half_t)w1, (half_t)w1};
        h2 w2h = h2{(half_t)w2, (half_t)w2};
#pragma unroll
        for (int j = 0; j < 4; ++j)
            acc2[j] += w1h * xvA[j] + w2h * xvB[j];
    }
    if (e < e1) {
        float q = edge_logit_h(nA, xr2, a06, a04, xvA);
#pragma unroll
        for (int d = 1; d < 16; d <<= 1) q += __shfl_xor(q, d, 64);
        float we = __expf(q);
        s += we;
        h2 weh = h2{(half_t)we, (half_t)we};
#pragma unroll
        for (int j = 0; j < 4; ++j) acc2[j] += weh * xvA[j];
    }
    float r = 1.f / (s + 1e-16f);
    half_t t[8];
#pragma unroll
    for (int j = 0; j < 4; ++j) {
#pragma unroll
        for (int p = 0; p < 2; ++p) {
            int c = cbase + 2 * j + p;
            float val = (float)acc2[j][p] * r + bias[c];
            float y = bng[c] * (val - bnm[c]) * rsqrtf(bnv[c] + 1e-5f) + bnb[c];
            t[2 * j + p] = (half_t)fmaxf(y, 0.f);
        }
    }
    uint4 qo;
    qo.x = u_bc(h2{t[0], t[1]});
    qo.y = u_bc(h2{t[2], t[3]});
    qo.z = u_bc(h2{t[4], t[5]});
    qo.w = u_bc(h2{t[6], t[7]});
    *(uint4*)(out_ + (size_t)node * HO + cbase) = qo;
}

// ---------------- mean pool (h2buf fp16 -> pooled fp32), vectorized ----------------
__global__ __launch_bounds__(128) void pool_kernel(const half_t* __restrict__ hb,
                                                   const int* __restrict__ gs,
                                                   float* __restrict__ pooled) {
    const int g = blockIdx.x;
    const int c4 = threadIdx.x * 4;   // 128 threads x 4 cols = 512
    const int s = gs[g], e = gs[g + 1];
    float a0 = 0.f, a1 = 0.f, a2 = 0.f, a3 = 0.f;
    for (int r = s; r < e; ++r) {
        uint2 q = *(const uint2*)(hb + (size_t)r * HO2 + c4);
        h2 p0 = h2_bc(q.x), p1 = h2_bc(q.y);
        a0 += (float)p0[0]; a1 += (float)p0[1];
        a2 += (float)p1[0]; a3 += (float)p1[1];
    }
    float inv = 1.f / fmaxf((float)(e - s), 1.f);
    float4 o; o.x = a0 * inv; o.y = a1 * inv; o.z = a2 * inv; o.w = a3 * inv;
    *(float4*)(pooled + (size_t)g * HO2 + c4) = o;
}

// ---------------- MLP head ----------------
__global__ __launch_bounds__(128) void mlp_kernel(const float* __restrict__ pooled,
                                                  const float* __restrict__ gf,
                                                  const float* __restrict__ fc1w,
                                                  const float* __restrict__ fc1b,
                                                  const float* __restrict__ fc2w,
                                                  const float* __restrict__ fc2b,
                                                  float* __restrict__ out) {
    __shared__ float z[704];
    __shared__ float red[2];
    const int g = blockIdx.x, t = threadIdx.x;
    for (int i = t; i < HO2; i += 128) z[i] = pooled[(size_t)g * HO2 + i];
    for (int i = t; i < GF_DIM; i += 128) z[HO2 + i] = gf[(size_t)g * GF_DIM + i];
    __syncthreads();
    float s = fc1b[t];
    for (int k = 0; k < Z_DIM; ++k) s += z[k] * fc1w[k * FC1_DIM + t];
    s = fmaxf(s, 0.f);              // relu (dropout = identity in eval)
    float c = s * fc2w[t];
#pragma unroll
    for (int d = 1; d < 64; d <<= 1) c += __shfl_xor(c, d, 64);
    if ((t & 63) == 0) red[t >> 6] = c;
    __syncthreads();
    if (t == 0) out[g] = red[0] + red[1] + fc2b[0];
}

// ---------------- launch ----------------
extern "C" void kernel_launch(void* const* d_in, const int* in_sizes, int n_in,
                              void* d_out, int out_size, void* d_ws, size_t ws_size,
                              hipStream_t stream) {
    float* out = (float*)d_out;
    if (ws_size < WS_REQUIRED) {
        diag_kernel<<<1, 256, 0, stream>>>(out, (float)(ws_size >> 20));
        return;
    }
    const float* x     = (const float*)d_in[0];
    const int*   ei    = (const int*)d_in[1];
    const int*   batch = (const int*)d_in[2];
    const float* gf    = (const float*)d_in[3];
    const float* Wl1   = (const float*)d_in[4];
    const float* bl1   = (const float*)d_in[5];
    const float* Wr1   = (const float*)d_in[6];
    const float* br1   = (const float*)d_in[7];
    const float* att1  = (const float*)d_in[8];
    const float* bias1 = (const float*)d_in[9];
    const float* bn1g  = (const float*)d_in[10];
    const float* bn1b  = (const float*)d_in[11];
    const float* bn1m  = (const float*)d_in[12];
    const float* bn1v  = (const float*)d_in[13];
    const float* Wl2   = (const float*)d_in[14];
    const float* bl2   = (const float*)d_in[15];
    const float* Wr2   = (const float*)d_in[16];
    const float* br2   = (const float*)d_in[17];
    const float* att2  = (const float*)d_in[18];
    const float* bias2 = (const float*)d_in[19];
    const float* bn2g  = (const float*)d_in[20];
    const float* bn2b  = (const float*)d_in[21];
    const float* bn2m  = (const float*)d_in[22];
    const float* bn2v  = (const float*)d_in[23];
    const float* fc1w  = (const float*)d_in[24];
    const float* fc1b  = (const float*)d_in[25];
    const float* fc2w  = (const float*)d_in[26];
    const float* fc2b  = (const float*)d_in[27];
    char* ws = (char*)d_ws;

    half_t* xl1  = (half_t*)(ws + OFF_XL1);
    half_t* xr1  = (half_t*)(ws + OFF_XR1);
    half_t* xlr2 = (half_t*)(ws + OFF_XLR2);
    half_t* h1   = (half_t*)(ws + OFF_H1);
    half_t* h2b  = (half_t*)(ws + OFF_H2);
    int* deg     = (int*)(ws + OFF_DEG);
    int* rowptr  = (int*)(ws + OFF_ROWPTR);
    int* cursor  = (int*)(ws + OFF_CURSOR);
    int* col     = (int*)(ws + OFF_COL);
    int* gs      = (int*)(ws + OFF_GS);
    float* pooled= (float*)(ws + OFF_POOLED);
    half_t* Wt   = (half_t*)(ws + OFF_WCAT);
    float* bcat  = (float*)(ws + OFF_BCAT);

    // fused setup (zero deg | gstart | pack W2) then CSR build
    setup_kernel<<<1221, 256, 0, stream>>>(deg, batch, gs, Wl2, Wr2, bl2, br2, Wt, bcat);
    count_kernel<<<(N_EDGES + 255) / 256, 256, 0, stream>>>(ei, deg);
    scan_kernel<<<1, 1024, 0, stream>>>(deg, rowptr, cursor);
    fill_kernel<<<(N_EDGES + 255) / 256, 256, 0, stream>>>(ei, cursor, col);

    // layer 1 (fp16 storage, fp32 linear); gat1: 4 edges/wave
    mm1_kernel<<<N_NODES / 8, 256, 0, stream>>>(x, Wl1, bl1, Wr1, br1, xl1, xr1);
    gat_node_kernel<64, 2><<<(N_NODES + 3) / 4, 256, 0, stream>>>(
        xl1, xr1, HO1, rowptr, col, att1, bias1, bn1g, bn1b, bn1m, bn1v, h1);

    // layer 2 (f16 MFMA GEMM, double-buffered + r8-shape gat2)
    mm2_mfma_kernel<<<dim3(8, (N_NODES + 127) / 128), 256, 0, stream>>>(h1, Wt, bcat, xlr2);
    gat2_kernel<128><<<(N_NODES + 3) / 4, 256, 0, stream>>>(
        xlr2, xlr2 + HO2, 1024, rowptr, col, att2, bias2, bn2g, bn2b, bn2m, bn2v, h2b);

    // pool + head
    pool_kernel<<<N_GRAPHS, 128, 0, stream>>>(h2b, gs, pooled);
    mlp_kernel<<<N_GRAPHS, 128, 0, stream>>>(pooled, gf, fc1w, fc1b, fc2w, fc2b, out);
}

// Round 14
// 694.316 us; speedup vs baseline: 1.0778x; 1.0778x over previous
//
#include <hip/hip_runtime.h>

#define N_NODES 50000
#define N_EDGES 800000
#define N_GRAPHS 256
#define F_IN 9
#define GF_DIM 187
#define HO1 256
#define HO2 512
#define FC1_DIM 128
#define Z_DIM (HO2 + GF_DIM)   // 699

// ---------------- workspace layout (bytes) — proven footprint ----------------
#define OFF_XL1   0UL
#define OFF_XR1   25600000UL
#define OFF_XLR2  0UL
#define OFF_H1    102400000UL
#define OFF_H2    102400000UL
#define OFF_SMALL 153600000UL
#define OFF_DEG    (OFF_SMALL + 0UL)
#define OFF_ROWPTR (OFF_SMALL + 200704UL)
#define OFF_CURSOR (OFF_SMALL + 401408UL)
#define OFF_COL    (OFF_SMALL + 602112UL)
#define OFF_GS     (OFF_SMALL + 3802112UL)
#define OFF_POOLED (OFF_SMALL + 3806208UL)
#define OFF_WCAT   (OFF_SMALL + 4330496UL)
#define OFF_BCAT   (OFF_SMALL + 5379072UL)
#define WS_REQUIRED (OFF_SMALL + 5383168UL)   // 158,983,168 (proven)

typedef _Float16 half_t;
typedef __attribute__((ext_vector_type(2))) _Float16 h2;
typedef __attribute__((ext_vector_type(8))) _Float16 half8;   // f16 MFMA frag
typedef __attribute__((ext_vector_type(4))) float floatx4;

__device__ __forceinline__ h2 h2_bc(unsigned u) { return __builtin_bit_cast(h2, u); }
__device__ __forceinline__ unsigned u_bc(h2 v) { return __builtin_bit_cast(unsigned, v); }

// async global->LDS, 16B per lane; LDS dest = wave-uniform base + lane*16
__device__ __forceinline__ void gl2lds16(const half_t* g, half_t* l) {
    __builtin_amdgcn_global_load_lds((const __attribute__((address_space(1))) void*)g,
                                     (__attribute__((address_space(3))) void*)l,
                                     16, 0, 0);
}

// packed logit step over 4 words (8 halves): q += a06.(xs+xr) + a04.|xs+xr|
__device__ __forceinline__ float edge_logit_h(const unsigned* w, const h2* xr2,
                                              const h2* a06, const h2* a04,
                                              h2* xv2) {
    float q = 0.f;
#pragma unroll
    for (int i = 0; i < 4; ++i) {
        h2 xs = h2_bc(w[i]);
        xv2[i] = xs;
        h2 v = xs + xr2[i];                       // v_pk_add_f16
        q = __builtin_amdgcn_fdot2(a06[i], v, q, false);
        h2 va = h2_bc(u_bc(v) & 0x7fff7fffu);     // packed abs
        q = __builtin_amdgcn_fdot2(a04[i], va, q, false);
    }
    return q;
}

// ---------------- diagnostic fallback (ws too small) ----------------
__global__ void diag_kernel(float* out, float v) { out[threadIdx.x] = v; }

// ---------------- fused setup: zero deg | graph starts | pack W2 ----------------
__global__ __launch_bounds__(256) void setup_kernel(int* __restrict__ deg,
                                                    const int* __restrict__ batch,
                                                    int* __restrict__ gs,
                                                    const float* __restrict__ Wl2,
                                                    const float* __restrict__ Wr2,
                                                    const float* __restrict__ bl2,
                                                    const float* __restrict__ br2,
                                                    half_t* __restrict__ Wt,
                                                    float* __restrict__ bcat) {
    const int b = blockIdx.x, t = threadIdx.x;
    if (b < 196) {
        int i = b * 256 + t;
        if (i < N_NODES) deg[i] = 0;
    } else if (b == 196) {
        int lo = 0, hi = N_NODES;
        while (lo < hi) {
            int mid = (lo + hi) >> 1;
            if (batch[mid] < t) lo = mid + 1; else hi = mid;
        }
        gs[t] = lo;
        if (t == 0) gs[N_GRAPHS] = N_NODES;
    } else {
        int i = (b - 197) * 256 + t;          // 0 .. 1024*256-1
        int n = i >> 8, k = i & 255;
        float w = (n < HO2) ? Wl2[k * HO2 + n] : Wr2[k * HO2 + (n - HO2)];
        Wt[i] = (half_t)w;
        if (i < 1024) bcat[i] = (i < HO2) ? bl2[i] : br2[i - HO2];
    }
}

// ---------------- CSR build ----------------
__global__ __launch_bounds__(256) void count_kernel(const int* __restrict__ ei,
                                                    int* __restrict__ deg) {
    int e = blockIdx.x * 256 + threadIdx.x;
    if (e < N_EDGES) atomicAdd(&deg[ei[N_EDGES + e]], 1);
}

__global__ __launch_bounds__(1024) void scan_kernel(const int* __restrict__ deg,
                                                    int* __restrict__ rowptr,
                                                    int* __restrict__ cursor) {
    __shared__ int part[1024];
    const int t = threadIdx.x;
    const int CH = (N_NODES + 1023) / 1024;   // 49
    int lo = t * CH;
    int hi = lo + CH; if (hi > N_NODES) hi = N_NODES;
    int s = 0;
    for (int i = lo; i < hi; ++i) s += deg[i];
    part[t] = s;
    __syncthreads();
    for (int off = 1; off < 1024; off <<= 1) {
        int v = (t >= off) ? part[t - off] : 0;
        __syncthreads();
        part[t] += v;
        __syncthreads();
    }
    int run = part[t] - s;  // exclusive base
    for (int i = lo; i < hi; ++i) {
        int d = deg[i];
        rowptr[i] = run;
        cursor[i] = run;
        run += d;
    }
    if (t == 1023) rowptr[N_NODES] = part[1023];
}

__global__ __launch_bounds__(256) void fill_kernel(const int* __restrict__ ei,
                                                   int* __restrict__ cursor,
                                                   int* __restrict__ col) {
    int e = blockIdx.x * 256 + threadIdx.x;
    if (e < N_EDGES) {
        int d = ei[N_EDGES + e];
        int pos = atomicAdd(&cursor[d], 1);
        col[pos] = ei[e];
    }
}

// ---------------- layer-1 linear (K=9), 8 nodes/block, fp16 out ----------------
__global__ __launch_bounds__(256) void mm1_kernel(const float* __restrict__ x,
                                                  const float* __restrict__ Wl,
                                                  const float* __restrict__ bl,
                                                  const float* __restrict__ Wr,
                                                  const float* __restrict__ br,
                                                  half_t* __restrict__ xl,
                                                  half_t* __restrict__ xr) {
    __shared__ float xs[8][F_IN];
    const int n0 = blockIdx.x * 8;           // N_NODES divisible by 8
    const int t = threadIdx.x;
    if (t < 8 * F_IN) xs[t / F_IN][t % F_IN] = x[n0 * F_IN + t];
    __syncthreads();
    const float blv = bl[t], brv = br[t];
    float sl[8], sr[8];
#pragma unroll
    for (int i = 0; i < 8; ++i) { sl[i] = blv; sr[i] = brv; }
#pragma unroll
    for (int k = 0; k < F_IN; ++k) {
        float wlk = Wl[k * HO1 + t];
        float wrk = Wr[k * HO1 + t];
#pragma unroll
        for (int i = 0; i < 8; ++i) {
            sl[i] = fmaf(xs[i][k], wlk, sl[i]);
            sr[i] = fmaf(xs[i][k], wrk, sr[i]);
        }
    }
#pragma unroll
    for (int i = 0; i < 8; ++i) {
        xl[(size_t)(n0 + i) * HO1 + t] = (half_t)sl[i];
        xr[(size_t)(n0 + i) * HO1 + t] = (half_t)sr[i];
    }
}

// ---------------- layer-2 linear: f16 MFMA, direct-to-LDS double-buffered ----------------
// Unpadded [128][32] LDS tiles: thread t's 16B chunk lands at byte t*16 —
// exactly the wave-uniform-base + lane*16 pattern global_load_lds writes.
__global__ __launch_bounds__(256) void mm2_mfma_kernel(
    const half_t* __restrict__ A,    // h1 fp16 [N,256]
    const half_t* __restrict__ Bt,   // Wt fp16 [1024][256]
    const float* __restrict__ bias,  // bcat [1024]
    half_t* __restrict__ C) {        // xlr2 fp16 [N,1024]
    __shared__ half_t As[2][128 * 32];  // 2 x 8 KB
    __shared__ half_t Bs[2][128 * 32];  // 2 x 8 KB
    const int t = threadIdx.x;
    const int lane = t & 63;
    const int w = t >> 6;
    const int wr = w >> 1, wc = w & 1;       // wave quadrant (64x64)
    const int l15 = lane & 15, kq = lane >> 4;
    const int row0 = blockIdx.y * 128;
    const int col0 = blockIdx.x * 128;

    const int c1 = t, c2 = t + 256;
    int ar1 = row0 + (c1 >> 2); ar1 = ar1 < N_NODES ? ar1 : N_NODES - 1;
    int ar2 = row0 + (c2 >> 2); ar2 = ar2 < N_NODES ? ar2 : N_NODES - 1;
    const half_t* pa1 = A + (size_t)ar1 * 256 + (c1 & 3) * 8;
    const half_t* pa2 = A + (size_t)ar2 * 256 + (c2 & 3) * 8;
    const half_t* pb1 = Bt + (size_t)(col0 + (c1 >> 2)) * 256 + (c1 & 3) * 8;
    const half_t* pb2 = Bt + (size_t)(col0 + (c2 >> 2)) * 256 + (c2 & 3) * 8;
    const int l1 = c1 * 8;      // halves: byte offset t*16
    const int l2 = c2 * 8;

    // prologue: stage k0=0 into buffer 0 (async, direct to LDS)
    gl2lds16(pa1, &As[0][l1]);
    gl2lds16(pa2, &As[0][l2]);
    gl2lds16(pb1, &Bs[0][l1]);
    gl2lds16(pb2, &Bs[0][l2]);

    floatx4 acc[4][4] = {};
    int buf = 0;
    for (int k0 = 0; k0 < 256; k0 += 32) {
        __syncthreads();             // drains vmcnt: LDS[buf] ready
        const bool more = (k0 + 32 < 256);
        if (more) {                  // async loads for next tile into other buffer
            int nb = 1 - buf;
            gl2lds16(pa1 + k0 + 32, &As[nb][l1]);
            gl2lds16(pa2 + k0 + 32, &As[nb][l2]);
            gl2lds16(pb1 + k0 + 32, &Bs[nb][l1]);
            gl2lds16(pb2 + k0 + 32, &Bs[nb][l2]);
        }
        half8 af[4], bf[4];
#pragma unroll
        for (int i = 0; i < 4; ++i)
            af[i] = *(const half8*)&As[buf][(wr * 64 + i * 16 + l15) * 32 + kq * 8];
#pragma unroll
        for (int j = 0; j < 4; ++j)
            bf[j] = *(const half8*)&Bs[buf][(wc * 64 + j * 16 + l15) * 32 + kq * 8];
#pragma unroll
        for (int i = 0; i < 4; ++i)
#pragma unroll
            for (int j = 0; j < 4; ++j)
                acc[i][j] = __builtin_amdgcn_mfma_f32_16x16x32_f16(
                    af[i], bf[j], acc[i][j], 0, 0, 0);
        if (more) buf = 1 - buf;
    }
#pragma unroll
    for (int j = 0; j < 4; ++j) {
        int col = col0 + wc * 64 + j * 16 + l15;
        float bj = bias[col];
#pragma unroll
        for (int i = 0; i < 4; ++i) {
            int rbase = row0 + wr * 64 + i * 16 + kq * 4;
            floatx4 v = acc[i][j];
#pragma unroll
            for (int r = 0; r < 4; ++r) {
                int row = rbase + r;
                if (row < N_NODES) C[(size_t)row * 1024 + col] = (half_t)(v[r] + bj);
            }
        }
    }
}

// ---------------- gat1: GROUPS=2 lane-split, packed fp16 math (r13, locked) ----------------
template <int O, int GROUPS>
__global__ __launch_bounds__(256, 4) void gat_node_kernel(
    const half_t* __restrict__ xl_, const half_t* __restrict__ xr_,
    int stride,
    const int* __restrict__ rowptr, const int* __restrict__ col,
    const float* __restrict__ att, const float* __restrict__ bias,
    const float* __restrict__ bng, const float* __restrict__ bnb,
    const float* __restrict__ bnm, const float* __restrict__ bnv,
    half_t* __restrict__ out_) {
    constexpr int TOT = 4 * O;
    constexpr int GS  = 64 / GROUPS;
    constexpr int VE  = TOT / GS;     // 8
    constexpr int LPH = O / VE;
    const int wave = threadIdx.x >> 6;
    const int node = blockIdx.x * 4 + wave;
    if (node >= N_NODES) return;
    const int lane = threadIdx.x & 63;
    const int gid  = lane / GS;
    const int gl   = lane % GS;
    const int cbase = gl * VE;

    h2 xr2[4], a06[4], a04[4], acc2[4], xvA[4], xvB[4];
    {
        uint4 q = *(const uint4*)(xr_ + (size_t)node * stride + cbase);
        xr2[0] = h2_bc(q.x); xr2[1] = h2_bc(q.y);
        xr2[2] = h2_bc(q.z); xr2[3] = h2_bc(q.w);
#pragma unroll
        for (int v = 0; v < VE; v += 4) {
            float4 b = *(const float4*)(att + cbase + v);
            a06[v / 2]     = h2{(half_t)(0.6f * b.x), (half_t)(0.6f * b.y)};
            a06[v / 2 + 1] = h2{(half_t)(0.6f * b.z), (half_t)(0.6f * b.w)};
            a04[v / 2]     = h2{(half_t)(0.4f * b.x), (half_t)(0.4f * b.y)};
            a04[v / 2 + 1] = h2{(half_t)(0.4f * b.z), (half_t)(0.4f * b.w)};
        }
    }
    float s;
    {
        unsigned w_[4];
        *(uint4*)w_ = *(const uint4*)(xl_ + (size_t)node * stride + cbase);
        float q = edge_logit_h(w_, xr2, a06, a04, xvA);
#pragma unroll
        for (int d = 1; d < LPH; d <<= 1) q += __shfl_xor(q, d, 64);
        float w0 = (GROUPS == 1 || gid == 0) ? __expf(q) : 0.f;
        s = w0;
        h2 w0h = h2{(half_t)w0, (half_t)w0};
#pragma unroll
        for (int j = 0; j < 4; ++j) acc2[j] = w0h * xvA[j];
    }

    const int e0 = rowptr[node], e1 = rowptr[node + 1];
    const int deg = e1 - e0;
    constexpr int PER = 2 * GROUPS;
    const int itc = (deg + PER - 1) / PER;
    const int elast = e1 - 1;
    int ia = e0 + 2 * gid;
    unsigned nA[4], nB[4];
    if (itc > 0) {
        int a = ia < elast ? ia : elast;
        int b = ia + 1 < elast ? ia + 1 : elast;
        *(uint4*)nA = *(const uint4*)(xl_ + (size_t)col[a] * stride + cbase);
        *(uint4*)nB = *(const uint4*)(xl_ + (size_t)col[b] * stride + cbase);
    }
    for (int k = 0; k < itc; ++k) {
        unsigned cA[4], cB[4];
#pragma unroll
        for (int i = 0; i < 4; ++i) { cA[i] = nA[i]; cB[i] = nB[i]; }
        int inext = ia + PER;
        if (k + 1 < itc) {
            int a = inext < elast ? inext : elast;
            int b = inext + 1 < elast ? inext + 1 : elast;
            *(uint4*)nA = *(const uint4*)(xl_ + (size_t)col[a] * stride + cbase);
            *(uint4*)nB = *(const uint4*)(xl_ + (size_t)col[b] * stride + cbase);
        }
        float q1 = edge_logit_h(cA, xr2, a06, a04, xvA);
        float q2 = edge_logit_h(cB, xr2, a06, a04, xvB);
#pragma unroll
        for (int d = 1; d < LPH; d <<= 1) {
            q1 += __shfl_xor(q1, d, 64);
            q2 += __shfl_xor(q2, d, 64);
        }
        float w1 = (ia < e1) ? __expf(q1) : 0.f;
        float w2 = (ia + 1 < e1) ? __expf(q2) : 0.f;
        s += w1 + w2;
        h2 w1h = h2{(half_t)w1, (half_t)w1};
        h2 w2h = h2{(half_t)w2, (half_t)w2};
#pragma unroll
        for (int j = 0; j < 4; ++j)
            acc2[j] += w1h * xvA[j] + w2h * xvB[j];
        ia = inext;
    }
    if constexpr (GROUPS == 2) {
        s += __shfl_xor(s, 32, 64);
#pragma unroll
        for (int j = 0; j < 4; ++j) {
            float tmp = __builtin_bit_cast(float, acc2[j]);
            float o = __shfl_xor(tmp, 32, 64);
            acc2[j] += __builtin_bit_cast(h2, o);
        }
    }
    float r = 1.f / (s + 1e-16f);
    if (GROUPS == 1 || gid == 0) {
        half_t t[8];
#pragma unroll
        for (int j = 0; j < 4; ++j) {
#pragma unroll
            for (int p = 0; p < 2; ++p) {
                int c = cbase + 2 * j + p;
                float val = (float)acc2[j][p] * r + bias[c];
                float y = bng[c] * (val - bnm[c]) * rsqrtf(bnv[c] + 1e-5f) + bnb[c];
                t[2 * j + p] = (half_t)fmaxf(y, 0.f);
            }
        }
        uint4 qo;
        qo.x = u_bc(h2{t[0], t[1]});
        qo.y = u_bc(h2{t[2], t[3]});
        qo.z = u_bc(h2{t[4], t[5]});
        qo.w = u_bc(h2{t[6], t[7]});
        *(uint4*)(out_ + (size_t)node * TOT + cbase) = qo;
    }
}

// ---------------- gat2: r8-exact loop shape, packed fp16 math (r13, locked) ----------------
template <int O>
__global__ __launch_bounds__(256, 4) void gat2_kernel(
    const half_t* __restrict__ xl_, const half_t* __restrict__ xr_,
    int stride,
    const int* __restrict__ rowptr, const int* __restrict__ col,
    const float* __restrict__ att, const float* __restrict__ bias,
    const float* __restrict__ bng, const float* __restrict__ bnb,
    const float* __restrict__ bnm, const float* __restrict__ bnv,
    half_t* __restrict__ out_) {
    constexpr int VE = O / 16;        // 8
    constexpr int HO = 4 * O;
    const int wave = threadIdx.x >> 6;
    const int node = blockIdx.x * 4 + wave;
    if (node >= N_NODES) return;
    const int lane = threadIdx.x & 63;
    const int l16 = lane & 15;
    const int cbase = (lane >> 4) * O + l16 * VE;

    h2 xr2[4], a06[4], a04[4], acc2[4], xvA[4], xvB[4];
    {
        uint4 q = *(const uint4*)(xr_ + (size_t)node * stride + cbase);
        xr2[0] = h2_bc(q.x); xr2[1] = h2_bc(q.y);
        xr2[2] = h2_bc(q.z); xr2[3] = h2_bc(q.w);
#pragma unroll
        for (int v = 0; v < VE; v += 4) {
            float4 b = *(const float4*)(att + cbase + v);
            a06[v / 2]     = h2{(half_t)(0.6f * b.x), (half_t)(0.6f * b.y)};
            a06[v / 2 + 1] = h2{(half_t)(0.6f * b.z), (half_t)(0.6f * b.w)};
            a04[v / 2]     = h2{(half_t)(0.4f * b.x), (half_t)(0.4f * b.y)};
            a04[v / 2 + 1] = h2{(half_t)(0.4f * b.z), (half_t)(0.4f * b.w)};
        }
    }
    float s;
    {
        unsigned ws_[4];
        *(uint4*)ws_ = *(const uint4*)(xl_ + (size_t)node * stride + cbase);
        float q = edge_logit_h(ws_, xr2, a06, a04, xvA);
#pragma unroll
        for (int d = 1; d < 16; d <<= 1) q += __shfl_xor(q, d, 64);
        float w0 = __expf(q);
        s = w0;
        h2 w0h = h2{(half_t)w0, (half_t)w0};
#pragma unroll
        for (int j = 0; j < 4; ++j) acc2[j] = w0h * xvA[j];
    }

    int e = rowptr[node];
    const int e1 = rowptr[node + 1];
    const int elast = e1 - 1;
    unsigned nA[4], nB[4];
    if (e < e1) *(uint4*)nA = *(const uint4*)(xl_ + (size_t)col[e] * stride + cbase);
    if (e + 1 < e1) *(uint4*)nB = *(const uint4*)(xl_ + (size_t)col[e + 1] * stride + cbase);
    while (e + 1 < e1) {
        unsigned cA[4], cB[4];
#pragma unroll
        for (int i = 0; i < 4; ++i) { cA[i] = nA[i]; cB[i] = nB[i]; }
        int i2 = e + 2 < elast ? e + 2 : elast;
        int i3 = e + 3 < elast ? e + 3 : elast;
        *(uint4*)nA = *(const uint4*)(xl_ + (size_t)col[i2] * stride + cbase);
        *(uint4*)nB = *(const uint4*)(xl_ + (size_t)col[i3] * stride + cbase);
        e += 2;
        float q1 = edge_logit_h(cA, xr2, a06, a04, xvA);
        float q2 = edge_logit_h(cB, xr2, a06, a04, xvB);
#pragma unroll
        for (int d = 1; d < 16; d <<= 1) {
            q1 += __shfl_xor(q1, d, 64);
            q2 += __shfl_xor(q2, d, 64);
        }
        float w1 = __expf(q1), w2 = __expf(q2);
        s += w1 + w2;
        h2 w1h = h2{(half_t)w1, (half_t)w1};
        h2 w2h = h2{(half_t)w2, (half_t)w2};
#pragma unroll
        for (int j = 0; j < 4; ++j)
            acc2[j] += w1h * xvA[j] + w2h * xvB[j];
    }
    if (e < e1) {
        float q = edge_logit_h(nA, xr2, a06, a04, xvA);
#pragma unroll
        for (int d = 1; d < 16; d <<= 1) q += __shfl_xor(q, d, 64);
        float we = __expf(q);
        s += we;
        h2 weh = h2{(half_t)we, (half_t)we};
#pragma unroll
        for (int j = 0; j < 4; ++j) acc2[j] += weh * xvA[j];
    }
    float r = 1.f / (s + 1e-16f);
    half_t t[8];
#pragma unroll
    for (int j = 0; j < 4; ++j) {
#pragma unroll
        for (int p = 0; p < 2; ++p) {
            int c = cbase + 2 * j + p;
            float val = (float)acc2[j][p] * r + bias[c];
            float y = bng[c] * (val - bnm[c]) * rsqrtf(bnv[c] + 1e-5f) + bnb[c];
            t[2 * j + p] = (half_t)fmaxf(y, 0.f);
        }
    }
    uint4 qo;
    qo.x = u_bc(h2{t[0], t[1]});
    qo.y = u_bc(h2{t[2], t[3]});
    qo.z = u_bc(h2{t[4], t[5]});
    qo.w = u_bc(h2{t[6], t[7]});
    *(uint4*)(out_ + (size_t)node * HO + cbase) = qo;
}

// ---------------- fused mean-pool + MLP head (one block per graph) ----------------
__global__ __launch_bounds__(256) void pool_mlp_kernel(const half_t* __restrict__ hb,
                                                       const int* __restrict__ gs,
                                                       const float* __restrict__ gf,
                                                       const float* __restrict__ fc1w,
                                                       const float* __restrict__ fc1b,
                                                       const float* __restrict__ fc2w,
                                                       const float* __restrict__ fc2b,
                                                       float* __restrict__ out) {
    __shared__ float z[704];
    __shared__ float red[2];
    const int g = blockIdx.x, t = threadIdx.x;
    const int s = gs[g], e = gs[g + 1];
    // pool: thread t covers cols 2t, 2t+1 (256 x 4B = 1KB coalesced per row)
    float a0 = 0.f, a1 = 0.f;
    for (int r = s; r < e; ++r) {
        unsigned q = *(const unsigned*)(hb + (size_t)r * HO2 + 2 * t);
        h2 p = h2_bc(q);
        a0 += (float)p[0]; a1 += (float)p[1];
    }
    float inv = 1.f / fmaxf((float)(e - s), 1.f);
    z[2 * t] = a0 * inv;
    z[2 * t + 1] = a1 * inv;
    if (t < GF_DIM) z[HO2 + t] = gf[(size_t)g * GF_DIM + t];
    __syncthreads();
    if (t < FC1_DIM) {              // waves 0,1 fully active
        float sv = fc1b[t];
        for (int k = 0; k < Z_DIM; ++k) sv += z[k] * fc1w[k * FC1_DIM + t];
        sv = fmaxf(sv, 0.f);        // relu (dropout = identity in eval)
        float c = sv * fc2w[t];
#pragma unroll
        for (int d = 1; d < 64; d <<= 1) c += __shfl_xor(c, d, 64);
        if ((t & 63) == 0) red[t >> 6] = c;
    }
    __syncthreads();
    if (t == 0) out[g] = red[0] + red[1] + fc2b[0];
}

// ---------------- launch ----------------
extern "C" void kernel_launch(void* const* d_in, const int* in_sizes, int n_in,
                              void* d_out, int out_size, void* d_ws, size_t ws_size,
                              hipStream_t stream) {
    float* out = (float*)d_out;
    if (ws_size < WS_REQUIRED) {
        diag_kernel<<<1, 256, 0, stream>>>(out, (float)(ws_size >> 20));
        return;
    }
    const float* x     = (const float*)d_in[0];
    const int*   ei    = (const int*)d_in[1];
    const int*   batch = (const int*)d_in[2];
    const float* gf    = (const float*)d_in[3];
    const float* Wl1   = (const float*)d_in[4];
    const float* bl1   = (const float*)d_in[5];
    const float* Wr1   = (const float*)d_in[6];
    const float* br1   = (const float*)d_in[7];
    const float* att1  = (const float*)d_in[8];
    const float* bias1 = (const float*)d_in[9];
    const float* bn1g  = (const float*)d_in[10];
    const float* bn1b  = (const float*)d_in[11];
    const float* bn1m  = (const float*)d_in[12];
    const float* bn1v  = (const float*)d_in[13];
    const float* Wl2   = (const float*)d_in[14];
    const float* bl2   = (const float*)d_in[15];
    const float* Wr2   = (const float*)d_in[16];
    const float* br2   = (const float*)d_in[17];
    const float* att2  = (const float*)d_in[18];
    const float* bias2 = (const float*)d_in[19];
    const float* bn2g  = (const float*)d_in[20];
    const float* bn2b  = (const float*)d_in[21];
    const float* bn2m  = (const float*)d_in[22];
    const float* bn2v  = (const float*)d_in[23];
    const float* fc1w  = (const float*)d_in[24];
    const float* fc1b  = (const float*)d_in[25];
    const float* fc2w  = (const float*)d_in[26];
    const float* fc2b  = (const float*)d_in[27];
    char* ws = (char*)d_ws;

    half_t* xl1  = (half_t*)(ws + OFF_XL1);
    half_t* xr1  = (half_t*)(ws + OFF_XR1);
    half_t* xlr2 = (half_t*)(ws + OFF_XLR2);
    half_t* h1   = (half_t*)(ws + OFF_H1);
    half_t* h2b  = (half_t*)(ws + OFF_H2);
    int* deg     = (int*)(ws + OFF_DEG);
    int* rowptr  = (int*)(ws + OFF_ROWPTR);
    int* cursor  = (int*)(ws + OFF_CURSOR);
    int* col     = (int*)(ws + OFF_COL);
    int* gs      = (int*)(ws + OFF_GS);
    half_t* Wt   = (half_t*)(ws + OFF_WCAT);
    float* bcat  = (float*)(ws + OFF_BCAT);

    // fused setup (zero deg | gstart | pack W2) then CSR build
    setup_kernel<<<1221, 256, 0, stream>>>(deg, batch, gs, Wl2, Wr2, bl2, br2, Wt, bcat);
    count_kernel<<<(N_EDGES + 255) / 256, 256, 0, stream>>>(ei, deg);
    scan_kernel<<<1, 1024, 0, stream>>>(deg, rowptr, cursor);
    fill_kernel<<<(N_EDGES + 255) / 256, 256, 0, stream>>>(ei, cursor, col);

    // layer 1 (fp16 storage, fp32 linear); gat1: 4 edges/wave
    mm1_kernel<<<N_NODES / 8, 256, 0, stream>>>(x, Wl1, bl1, Wr1, br1, xl1, xr1);
    gat_node_kernel<64, 2><<<(N_NODES + 3) / 4, 256, 0, stream>>>(
        xl1, xr1, HO1, rowptr, col, att1, bias1, bn1g, bn1b, bn1m, bn1v, h1);

    // layer 2 (f16 MFMA GEMM, direct-to-LDS dbuf + r8-shape gat2)
    mm2_mfma_kernel<<<dim3(8, (N_NODES + 127) / 128), 256, 0, stream>>>(h1, Wt, bcat, xlr2);
    gat2_kernel<128><<<(N_NODES + 3) / 4, 256, 0, stream>>>(
        xlr2, xlr2 + HO2, 1024, rowptr, col, att2, bias2, bn2g, bn2b, bn2m, bn2v, h2b);

    // fused pool + head
    pool_mlp_kernel<<<N_GRAPHS, 256, 0, stream>>>(h2b, gs, gf, fc1w, fc1b, fc2w, fc2b, out);
}

// Round 15
// 673.552 us; speedup vs baseline: 1.1110x; 1.0308x over previous
//
#include <hip/hip_runtime.h>

#define N_NODES 50000
#define N_EDGES 800000
#define N_GRAPHS 256
#define F_IN 9
#define GF_DIM 187
#define HO1 256
#define HO2 512
#define FC1_DIM 128
#define Z_DIM (HO2 + GF_DIM)   // 699

// ---------------- workspace layout (bytes) — proven footprint ----------------
#define OFF_XL1   0UL
#define OFF_XR1   25600000UL
#define OFF_XLR2  0UL
#define OFF_H1    102400000UL
#define OFF_H2    102400000UL
#define OFF_SMALL 153600000UL
#define OFF_DEG    (OFF_SMALL + 0UL)
#define OFF_ROWPTR (OFF_SMALL + 200704UL)
#define OFF_CURSOR (OFF_SMALL + 401408UL)
#define OFF_COL    (OFF_SMALL + 602112UL)
#define OFF_GS     (OFF_SMALL + 3802112UL)
#define OFF_POOLED (OFF_SMALL + 3806208UL)   // 512 KB fp32 pooled
#define OFF_WCAT   (OFF_SMALL + 4330496UL)
#define OFF_BCAT   (OFF_SMALL + 5379072UL)
#define WS_REQUIRED (OFF_SMALL + 5383168UL)   // 158,983,168 (proven)

typedef _Float16 half_t;
typedef __attribute__((ext_vector_type(2))) _Float16 h2;
typedef __attribute__((ext_vector_type(8))) _Float16 half8;   // f16 MFMA frag
typedef __attribute__((ext_vector_type(4))) float floatx4;

__device__ __forceinline__ h2 h2_bc(unsigned u) { return __builtin_bit_cast(h2, u); }
__device__ __forceinline__ unsigned u_bc(h2 v) { return __builtin_bit_cast(unsigned, v); }

// async global->LDS, 16B per lane; LDS dest = wave-uniform base + lane*16
__device__ __forceinline__ void gl2lds16(const half_t* g, half_t* l) {
    __builtin_amdgcn_global_load_lds((const __attribute__((address_space(1))) void*)g,
                                     (__attribute__((address_space(3))) void*)l,
                                     16, 0, 0);
}

// packed logit step over 4 words (8 halves): q += a06.(xs+xr) + a04.|xs+xr|
__device__ __forceinline__ float edge_logit_h(const unsigned* w, const h2* xr2,
                                              const h2* a06, const h2* a04,
                                              h2* xv2) {
    float q = 0.f;
#pragma unroll
    for (int i = 0; i < 4; ++i) {
        h2 xs = h2_bc(w[i]);
        xv2[i] = xs;
        h2 v = xs + xr2[i];                       // v_pk_add_f16
        q = __builtin_amdgcn_fdot2(a06[i], v, q, false);
        h2 va = h2_bc(u_bc(v) & 0x7fff7fffu);     // packed abs
        q = __builtin_amdgcn_fdot2(a04[i], va, q, false);
    }
    return q;
}

// ---------------- diagnostic fallback (ws too small) ----------------
__global__ void diag_kernel(float* out, float v) { out[threadIdx.x] = v; }

// ---------------- fused setup: zero deg | graph starts | pack W2 ----------------
__global__ __launch_bounds__(256) void setup_kernel(int* __restrict__ deg,
                                                    const int* __restrict__ batch,
                                                    int* __restrict__ gs,
                                                    const float* __restrict__ Wl2,
                                                    const float* __restrict__ Wr2,
                                                    const float* __restrict__ bl2,
                                                    const float* __restrict__ br2,
                                                    half_t* __restrict__ Wt,
                                                    float* __restrict__ bcat) {
    const int b = blockIdx.x, t = threadIdx.x;
    if (b < 196) {
        int i = b * 256 + t;
        if (i < N_NODES) deg[i] = 0;
    } else if (b == 196) {
        int lo = 0, hi = N_NODES;
        while (lo < hi) {
            int mid = (lo + hi) >> 1;
            if (batch[mid] < t) lo = mid + 1; else hi = mid;
        }
        gs[t] = lo;
        if (t == 0) gs[N_GRAPHS] = N_NODES;
    } else {
        int i = (b - 197) * 256 + t;          // 0 .. 1024*256-1
        int n = i >> 8, k = i & 255;
        float w = (n < HO2) ? Wl2[k * HO2 + n] : Wr2[k * HO2 + (n - HO2)];
        Wt[i] = (half_t)w;
        if (i < 1024) bcat[i] = (i < HO2) ? bl2[i] : br2[i - HO2];
    }
}

// ---------------- CSR build ----------------
__global__ __launch_bounds__(256) void count_kernel(const int* __restrict__ ei,
                                                    int* __restrict__ deg) {
    int e = blockIdx.x * 256 + threadIdx.x;
    if (e < N_EDGES) atomicAdd(&deg[ei[N_EDGES + e]], 1);
}

__global__ __launch_bounds__(1024) void scan_kernel(const int* __restrict__ deg,
                                                    int* __restrict__ rowptr,
                                                    int* __restrict__ cursor) {
    __shared__ int part[1024];
    const int t = threadIdx.x;
    const int CH = (N_NODES + 1023) / 1024;   // 49
    int lo = t * CH;
    int hi = lo + CH; if (hi > N_NODES) hi = N_NODES;
    int s = 0;
    for (int i = lo; i < hi; ++i) s += deg[i];
    part[t] = s;
    __syncthreads();
    for (int off = 1; off < 1024; off <<= 1) {
        int v = (t >= off) ? part[t - off] : 0;
        __syncthreads();
        part[t] += v;
        __syncthreads();
    }
    int run = part[t] - s;  // exclusive base
    for (int i = lo; i < hi; ++i) {
        int d = deg[i];
        rowptr[i] = run;
        cursor[i] = run;
        run += d;
    }
    if (t == 1023) rowptr[N_NODES] = part[1023];
}

__global__ __launch_bounds__(256) void fill_kernel(const int* __restrict__ ei,
                                                   int* __restrict__ cursor,
                                                   int* __restrict__ col) {
    int e = blockIdx.x * 256 + threadIdx.x;
    if (e < N_EDGES) {
        int d = ei[N_EDGES + e];
        int pos = atomicAdd(&cursor[d], 1);
        col[pos] = ei[e];
    }
}

// ---------------- layer-1 linear (K=9), 8 nodes/block, fp16 out ----------------
__global__ __launch_bounds__(256) void mm1_kernel(const float* __restrict__ x,
                                                  const float* __restrict__ Wl,
                                                  const float* __restrict__ bl,
                                                  const float* __restrict__ Wr,
                                                  const float* __restrict__ br,
                                                  half_t* __restrict__ xl,
                                                  half_t* __restrict__ xr) {
    __shared__ float xs[8][F_IN];
    const int n0 = blockIdx.x * 8;           // N_NODES divisible by 8
    const int t = threadIdx.x;
    if (t < 8 * F_IN) xs[t / F_IN][t % F_IN] = x[n0 * F_IN + t];
    __syncthreads();
    const float blv = bl[t], brv = br[t];
    float sl[8], sr[8];
#pragma unroll
    for (int i = 0; i < 8; ++i) { sl[i] = blv; sr[i] = brv; }
#pragma unroll
    for (int k = 0; k < F_IN; ++k) {
        float wlk = Wl[k * HO1 + t];
        float wrk = Wr[k * HO1 + t];
#pragma unroll
        for (int i = 0; i < 8; ++i) {
            sl[i] = fmaf(xs[i][k], wlk, sl[i]);
            sr[i] = fmaf(xs[i][k], wrk, sr[i]);
        }
    }
#pragma unroll
    for (int i = 0; i < 8; ++i) {
        xl[(size_t)(n0 + i) * HO1 + t] = (half_t)sl[i];
        xr[(size_t)(n0 + i) * HO1 + t] = (half_t)sr[i];
    }
}

// ---------------- layer-2 linear: f16 MFMA, direct-to-LDS double-buffered ----------------
__global__ __launch_bounds__(256) void mm2_mfma_kernel(
    const half_t* __restrict__ A,    // h1 fp16 [N,256]
    const half_t* __restrict__ Bt,   // Wt fp16 [1024][256]
    const float* __restrict__ bias,  // bcat [1024]
    half_t* __restrict__ C) {        // xlr2 fp16 [N,1024]
    __shared__ half_t As[2][128 * 32];  // 2 x 8 KB
    __shared__ half_t Bs[2][128 * 32];  // 2 x 8 KB
    const int t = threadIdx.x;
    const int lane = t & 63;
    const int w = t >> 6;
    const int wr = w >> 1, wc = w & 1;       // wave quadrant (64x64)
    const int l15 = lane & 15, kq = lane >> 4;
    const int row0 = blockIdx.y * 128;
    const int col0 = blockIdx.x * 128;

    const int c1 = t, c2 = t + 256;
    int ar1 = row0 + (c1 >> 2); ar1 = ar1 < N_NODES ? ar1 : N_NODES - 1;
    int ar2 = row0 + (c2 >> 2); ar2 = ar2 < N_NODES ? ar2 : N_NODES - 1;
    const half_t* pa1 = A + (size_t)ar1 * 256 + (c1 & 3) * 8;
    const half_t* pa2 = A + (size_t)ar2 * 256 + (c2 & 3) * 8;
    const half_t* pb1 = Bt + (size_t)(col0 + (c1 >> 2)) * 256 + (c1 & 3) * 8;
    const half_t* pb2 = Bt + (size_t)(col0 + (c2 >> 2)) * 256 + (c2 & 3) * 8;
    const int l1 = c1 * 8;      // halves: byte offset t*16
    const int l2 = c2 * 8;

    gl2lds16(pa1, &As[0][l1]);
    gl2lds16(pa2, &As[0][l2]);
    gl2lds16(pb1, &Bs[0][l1]);
    gl2lds16(pb2, &Bs[0][l2]);

    floatx4 acc[4][4] = {};
    int buf = 0;
    for (int k0 = 0; k0 < 256; k0 += 32) {
        __syncthreads();             // drains vmcnt: LDS[buf] ready
        const bool more = (k0 + 32 < 256);
        if (more) {
            int nb = 1 - buf;
            gl2lds16(pa1 + k0 + 32, &As[nb][l1]);
            gl2lds16(pa2 + k0 + 32, &As[nb][l2]);
            gl2lds16(pb1 + k0 + 32, &Bs[nb][l1]);
            gl2lds16(pb2 + k0 + 32, &Bs[nb][l2]);
        }
        half8 af[4], bf[4];
#pragma unroll
        for (int i = 0; i < 4; ++i)
            af[i] = *(const half8*)&As[buf][(wr * 64 + i * 16 + l15) * 32 + kq * 8];
#pragma unroll
        for (int j = 0; j < 4; ++j)
            bf[j] = *(const half8*)&Bs[buf][(wc * 64 + j * 16 + l15) * 32 + kq * 8];
#pragma unroll
        for (int i = 0; i < 4; ++i)
#pragma unroll
            for (int j = 0; j < 4; ++j)
                acc[i][j] = __builtin_amdgcn_mfma_f32_16x16x32_f16(
                    af[i], bf[j], acc[i][j], 0, 0, 0);
        if (more) buf = 1 - buf;
    }
#pragma unroll
    for (int j = 0; j < 4; ++j) {
        int col = col0 + wc * 64 + j * 16 + l15;
        float bj = bias[col];
#pragma unroll
        for (int i = 0; i < 4; ++i) {
            int rbase = row0 + wr * 64 + i * 16 + kq * 4;
            floatx4 v = acc[i][j];
#pragma unroll
            for (int r = 0; r < 4; ++r) {
                int row = rbase + r;
                if (row < N_NODES) C[(size_t)row * 1024 + col] = (half_t)(v[r] + bj);
            }
        }
    }
}

// ---------------- gat1: GROUPS=2 lane-split, packed fp16 math (locked) ----------------
template <int O, int GROUPS>
__global__ __launch_bounds__(256, 4) void gat_node_kernel(
    const half_t* __restrict__ xl_, const half_t* __restrict__ xr_,
    int stride,
    const int* __restrict__ rowptr, const int* __restrict__ col,
    const float* __restrict__ att, const float* __restrict__ bias,
    const float* __restrict__ bng, const float* __restrict__ bnb,
    const float* __restrict__ bnm, const float* __restrict__ bnv,
    half_t* __restrict__ out_) {
    constexpr int TOT = 4 * O;
    constexpr int GS  = 64 / GROUPS;
    constexpr int VE  = TOT / GS;     // 8
    constexpr int LPH = O / VE;
    const int wave = threadIdx.x >> 6;
    const int node = blockIdx.x * 4 + wave;
    if (node >= N_NODES) return;
    const int lane = threadIdx.x & 63;
    const int gid  = lane / GS;
    const int gl   = lane % GS;
    const int cbase = gl * VE;

    h2 xr2[4], a06[4], a04[4], acc2[4], xvA[4], xvB[4];
    {
        uint4 q = *(const uint4*)(xr_ + (size_t)node * stride + cbase);
        xr2[0] = h2_bc(q.x); xr2[1] = h2_bc(q.y);
        xr2[2] = h2_bc(q.z); xr2[3] = h2_bc(q.w);
#pragma unroll
        for (int v = 0; v < VE; v += 4) {
            float4 b = *(const float4*)(att + cbase + v);
            a06[v / 2]     = h2{(half_t)(0.6f * b.x), (half_t)(0.6f * b.y)};
            a06[v / 2 + 1] = h2{(half_t)(0.6f * b.z), (half_t)(0.6f * b.w)};
            a04[v / 2]     = h2{(half_t)(0.4f * b.x), (half_t)(0.4f * b.y)};
            a04[v / 2 + 1] = h2{(half_t)(0.4f * b.z), (half_t)(0.4f * b.w)};
        }
    }
    float s;
    {
        unsigned w_[4];
        *(uint4*)w_ = *(const uint4*)(xl_ + (size_t)node * stride + cbase);
        float q = edge_logit_h(w_, xr2, a06, a04, xvA);
#pragma unroll
        for (int d = 1; d < LPH; d <<= 1) q += __shfl_xor(q, d, 64);
        float w0 = (GROUPS == 1 || gid == 0) ? __expf(q) : 0.f;
        s = w0;
        h2 w0h = h2{(half_t)w0, (half_t)w0};
#pragma unroll
        for (int j = 0; j < 4; ++j) acc2[j] = w0h * xvA[j];
    }

    const int e0 = rowptr[node], e1 = rowptr[node + 1];
    const int deg = e1 - e0;
    constexpr int PER = 2 * GROUPS;
    const int itc = (deg + PER - 1) / PER;
    const int elast = e1 - 1;
    int ia = e0 + 2 * gid;
    unsigned nA[4], nB[4];
    if (itc > 0) {
        int a = ia < elast ? ia : elast;
        int b = ia + 1 < elast ? ia + 1 : elast;
        *(uint4*)nA = *(const uint4*)(xl_ + (size_t)col[a] * stride + cbase);
        *(uint4*)nB = *(const uint4*)(xl_ + (size_t)col[b] * stride + cbase);
    }
    for (int k = 0; k < itc; ++k) {
        unsigned cA[4], cB[4];
#pragma unroll
        for (int i = 0; i < 4; ++i) { cA[i] = nA[i]; cB[i] = nB[i]; }
        int inext = ia + PER;
        if (k + 1 < itc) {
            int a = inext < elast ? inext : elast;
            int b = inext + 1 < elast ? inext + 1 : elast;
            *(uint4*)nA = *(const uint4*)(xl_ + (size_t)col[a] * stride + cbase);
            *(uint4*)nB = *(const uint4*)(xl_ + (size_t)col[b] * stride + cbase);
        }
        float q1 = edge_logit_h(cA, xr2, a06, a04, xvA);
        float q2 = edge_logit_h(cB, xr2, a06, a04, xvB);
#pragma unroll
        for (int d = 1; d < LPH; d <<= 1) {
            q1 += __shfl_xor(q1, d, 64);
            q2 += __shfl_xor(q2, d, 64);
        }
        float w1 = (ia < e1) ? __expf(q1) : 0.f;
        float w2 = (ia + 1 < e1) ? __expf(q2) : 0.f;
        s += w1 + w2;
        h2 w1h = h2{(half_t)w1, (half_t)w1};
        h2 w2h = h2{(half_t)w2, (half_t)w2};
#pragma unroll
        for (int j = 0; j < 4; ++j)
            acc2[j] += w1h * xvA[j] + w2h * xvB[j];
        ia = inext;
    }
    if constexpr (GROUPS == 2) {
        s += __shfl_xor(s, 32, 64);
#pragma unroll
        for (int j = 0; j < 4; ++j) {
            float tmp = __builtin_bit_cast(float, acc2[j]);
            float o = __shfl_xor(tmp, 32, 64);
            acc2[j] += __builtin_bit_cast(h2, o);
        }
    }
    float r = 1.f / (s + 1e-16f);
    if (GROUPS == 1 || gid == 0) {
        half_t t[8];
#pragma unroll
        for (int j = 0; j < 4; ++j) {
#pragma unroll
            for (int p = 0; p < 2; ++p) {
                int c = cbase + 2 * j + p;
                float val = (float)acc2[j][p] * r + bias[c];
                float y = bng[c] * (val - bnm[c]) * rsqrtf(bnv[c] + 1e-5f) + bnb[c];
                t[2 * j + p] = (half_t)fmaxf(y, 0.f);
            }
        }
        uint4 qo;
        qo.x = u_bc(h2{t[0], t[1]});
        qo.y = u_bc(h2{t[2], t[3]});
        qo.z = u_bc(h2{t[4], t[5]});
        qo.w = u_bc(h2{t[6], t[7]});
        *(uint4*)(out_ + (size_t)node * TOT + cbase) = qo;
    }
}

// ---------------- gat2: r8-exact loop shape, packed fp16 math (locked) ----------------
template <int O>
__global__ __launch_bounds__(256, 4) void gat2_kernel(
    const half_t* __restrict__ xl_, const half_t* __restrict__ xr_,
    int stride,
    const int* __restrict__ rowptr, const int* __restrict__ col,
    const float* __restrict__ att, const float* __restrict__ bias,
    const float* __restrict__ bng, const float* __restrict__ bnb,
    const float* __restrict__ bnm, const float* __restrict__ bnv,
    half_t* __restrict__ out_) {
    constexpr int VE = O / 16;        // 8
    constexpr int HO = 4 * O;
    const int wave = threadIdx.x >> 6;
    const int node = blockIdx.x * 4 + wave;
    if (node >= N_NODES) return;
    const int lane = threadIdx.x & 63;
    const int l16 = lane & 15;
    const int cbase = (lane >> 4) * O + l16 * VE;

    h2 xr2[4], a06[4], a04[4], acc2[4], xvA[4], xvB[4];
    {
        uint4 q = *(const uint4*)(xr_ + (size_t)node * stride + cbase);
        xr2[0] = h2_bc(q.x); xr2[1] = h2_bc(q.y);
        xr2[2] = h2_bc(q.z); xr2[3] = h2_bc(q.w);
#pragma unroll
        for (int v = 0; v < VE; v += 4) {
            float4 b = *(const float4*)(att + cbase + v);
            a06[v / 2]     = h2{(half_t)(0.6f * b.x), (half_t)(0.6f * b.y)};
            a06[v / 2 + 1] = h2{(half_t)(0.6f * b.z), (half_t)(0.6f * b.w)};
            a04[v / 2]     = h2{(half_t)(0.4f * b.x), (half_t)(0.4f * b.y)};
            a04[v / 2 + 1] = h2{(half_t)(0.4f * b.z), (half_t)(0.4f * b.w)};
        }
    }
    float s;
    {
        unsigned ws_[4];
        *(uint4*)ws_ = *(const uint4*)(xl_ + (size_t)node * stride + cbase);
        float q = edge_logit_h(ws_, xr2, a06, a04, xvA);
#pragma unroll
        for (int d = 1; d < 16; d <<= 1) q += __shfl_xor(q, d, 64);
        float w0 = __expf(q);
        s = w0;
        h2 w0h = h2{(half_t)w0, (half_t)w0};
#pragma unroll
        for (int j = 0; j < 4; ++j) acc2[j] = w0h * xvA[j];
    }

    int e = rowptr[node];
    const int e1 = rowptr[node + 1];
    const int elast = e1 - 1;
    unsigned nA[4], nB[4];
    if (e < e1) *(uint4*)nA = *(const uint4*)(xl_ + (size_t)col[e] * stride + cbase);
    if (e + 1 < e1) *(uint4*)nB = *(const uint4*)(xl_ + (size_t)col[e + 1] * stride + cbase);
    while (e + 1 < e1) {
        unsigned cA[4], cB[4];
#pragma unroll
        for (int i = 0; i < 4; ++i) { cA[i] = nA[i]; cB[i] = nB[i]; }
        int i2 = e + 2 < elast ? e + 2 : elast;
        int i3 = e + 3 < elast ? e + 3 : elast;
        *(uint4*)nA = *(const uint4*)(xl_ + (size_t)col[i2] * stride + cbase);
        *(uint4*)nB = *(const uint4*)(xl_ + (size_t)col[i3] * stride + cbase);
        e += 2;
        float q1 = edge_logit_h(cA, xr2, a06, a04, xvA);
        float q2 = edge_logit_h(cB, xr2, a06, a04, xvB);
#pragma unroll
        for (int d = 1; d < 16; d <<= 1) {
            q1 += __shfl_xor(q1, d, 64);
            q2 += __shfl_xor(q2, d, 64);
        }
        float w1 = __expf(q1), w2 = __expf(q2);
        s += w1 + w2;
        h2 w1h = h2{(half_t)w1, (half_t)w1};
        h2 w2h = h2{(half_t)w2, (half_t)w2};
#pragma unroll
        for (int j = 0; j < 4; ++j)
            acc2[j] += w1h * xvA[j] + w2h * xvB[j];
    }
    if (e < e1) {
        float q = edge_logit_h(nA, xr2, a06, a04, xvA);
#pragma unroll
        for (int d = 1; d < 16; d <<= 1) q += __shfl_xor(q, d, 64);
        float we = __expf(q);
        s += we;
        h2 weh = h2{(half_t)we, (half_t)we};
#pragma unroll
        for (int j = 0; j < 4; ++j) acc2[j] += weh * xvA[j];
    }
    float r = 1.f / (s + 1e-16f);
    half_t t[8];
#pragma unroll
    for (int j = 0; j < 4; ++j) {
#pragma unroll
        for (int p = 0; p < 2; ++p) {
            int c = cbase + 2 * j + p;
            float val = (float)acc2[j][p] * r + bias[c];
            float y = bng[c] * (val - bnm[c]) * rsqrtf(bnv[c] + 1e-5f) + bnb[c];
            t[2 * j + p] = (half_t)fmaxf(y, 0.f);
        }
    }
    uint4 qo;
    qo.x = u_bc(h2{t[0], t[1]});
    qo.y = u_bc(h2{t[2], t[3]});
    qo.z = u_bc(h2{t[4], t[5]});
    qo.w = u_bc(h2{t[6], t[7]});
    *(uint4*)(out_ + (size_t)node * HO + cbase) = qo;
}

// ---------------- mean pool: 4 blocks/graph x 4 row-stripes (high TLP) ----------------
// block = (graph g, col-quarter q); thread = (stripe p = t>>6, word w = t&63).
// Each thread sums rows s+p, s+p+4, ... for cols [q*128 + w*2, +1]; cross-stripe
// reduce via LDS; 1024 blocks x 16 waves/CU hides the gather latency.
__global__ __launch_bounds__(256) void pool_kernel(const half_t* __restrict__ hb,
                                                   const int* __restrict__ gs,
                                                   float* __restrict__ pooled) {
    __shared__ float red[4][128];
    const int g = blockIdx.x >> 2;
    const int q = blockIdx.x & 3;
    const int t = threadIdx.x;
    const int p = t >> 6, w = t & 63;
    const int s = gs[g], e = gs[g + 1];
    const half_t* base = hb + (size_t)0 * HO2 + q * 128 + w * 2;
    float a0 = 0.f, a1 = 0.f;
    for (int r = s + p; r < e; r += 4) {
        unsigned u = *(const unsigned*)(base + (size_t)r * HO2);
        h2 v = h2_bc(u);
        a0 += (float)v[0];
        a1 += (float)v[1];
    }
    red[p][w * 2] = a0;
    red[p][w * 2 + 1] = a1;
    __syncthreads();
    if (p == 0) {
        float inv = 1.f / fmaxf((float)(e - s), 1.f);
        float v0 = (red[0][w * 2] + red[1][w * 2] + red[2][w * 2] + red[3][w * 2]) * inv;
        float v1 = (red[0][w * 2 + 1] + red[1][w * 2 + 1] + red[2][w * 2 + 1] + red[3][w * 2 + 1]) * inv;
        float2 o; o.x = v0; o.y = v1;
        *(float2*)(pooled + (size_t)g * HO2 + q * 128 + w * 2) = o;
    }
}

// ---------------- MLP head ----------------
__global__ __launch_bounds__(128) void mlp_kernel(const float* __restrict__ pooled,
                                                  const float* __restrict__ gf,
                                                  const float* __restrict__ fc1w,
                                                  const float* __restrict__ fc1b,
                                                  const float* __restrict__ fc2w,
                                                  const float* __restrict__ fc2b,
                                                  float* __restrict__ out) {
    __shared__ float z[704];
    __shared__ float red[2];
    const int g = blockIdx.x, t = threadIdx.x;
    for (int i = t; i < HO2; i += 128) z[i] = pooled[(size_t)g * HO2 + i];
    for (int i = t; i < GF_DIM; i += 128) z[HO2 + i] = gf[(size_t)g * GF_DIM + i];
    __syncthreads();
    float s = fc1b[t];
    for (int k = 0; k < Z_DIM; ++k) s += z[k] * fc1w[k * FC1_DIM + t];
    s = fmaxf(s, 0.f);              // relu (dropout = identity in eval)
    float c = s * fc2w[t];
#pragma unroll
    for (int d = 1; d < 64; d <<= 1) c += __shfl_xor(c, d, 64);
    if ((t & 63) == 0) red[t >> 6] = c;
    __syncthreads();
    if (t == 0) out[g] = red[0] + red[1] + fc2b[0];
}

// ---------------- launch ----------------
extern "C" void kernel_launch(void* const* d_in, const int* in_sizes, int n_in,
                              void* d_out, int out_size, void* d_ws, size_t ws_size,
                              hipStream_t stream) {
    float* out = (float*)d_out;
    if (ws_size < WS_REQUIRED) {
        diag_kernel<<<1, 256, 0, stream>>>(out, (float)(ws_size >> 20));
        return;
    }
    const float* x     = (const float*)d_in[0];
    const int*   ei    = (const int*)d_in[1];
    const int*   batch = (const int*)d_in[2];
    const float* gf    = (const float*)d_in[3];
    const float* Wl1   = (const float*)d_in[4];
    const float* bl1   = (const float*)d_in[5];
    const float* Wr1   = (const float*)d_in[6];
    const float* br1   = (const float*)d_in[7];
    const float* att1  = (const float*)d_in[8];
    const float* bias1 = (const float*)d_in[9];
    const float* bn1g  = (const float*)d_in[10];
    const float* bn1b  = (const float*)d_in[11];
    const float* bn1m  = (const float*)d_in[12];
    const float* bn1v  = (const float*)d_in[13];
    const float* Wl2   = (const float*)d_in[14];
    const float* bl2   = (const float*)d_in[15];
    const float* Wr2   = (const float*)d_in[16];
    const float* br2   = (const float*)d_in[17];
    const float* att2  = (const float*)d_in[18];
    const float* bias2 = (const float*)d_in[19];
    const float* bn2g  = (const float*)d_in[20];
    const float* bn2b  = (const float*)d_in[21];
    const float* bn2m  = (const float*)d_in[22];
    const float* bn2v  = (const float*)d_in[23];
    const float* fc1w  = (const float*)d_in[24];
    const float* fc1b  = (const float*)d_in[25];
    const float* fc2w  = (const float*)d_in[26];
    const float* fc2b  = (const float*)d_in[27];
    char* ws = (char*)d_ws;

    half_t* xl1  = (half_t*)(ws + OFF_XL1);
    half_t* xr1  = (half_t*)(ws + OFF_XR1);
    half_t* xlr2 = (half_t*)(ws + OFF_XLR2);
    half_t* h1   = (half_t*)(ws + OFF_H1);
    half_t* h2b  = (half_t*)(ws + OFF_H2);
    int* deg     = (int*)(ws + OFF_DEG);
    int* rowptr  = (int*)(ws + OFF_ROWPTR);
    int* cursor  = (int*)(ws + OFF_CURSOR);
    int* col     = (int*)(ws + OFF_COL);
    int* gs      = (int*)(ws + OFF_GS);
    float* pooled= (float*)(ws + OFF_POOLED);
    half_t* Wt   = (half_t*)(ws + OFF_WCAT);
    float* bcat  = (float*)(ws + OFF_BCAT);

    // fused setup (zero deg | gstart | pack W2) then CSR build
    setup_kernel<<<1221, 256, 0, stream>>>(deg, batch, gs, Wl2, Wr2, bl2, br2, Wt, bcat);
    count_kernel<<<(N_EDGES + 255) / 256, 256, 0, stream>>>(ei, deg);
    scan_kernel<<<1, 1024, 0, stream>>>(deg, rowptr, cursor);
    fill_kernel<<<(N_EDGES + 255) / 256, 256, 0, stream>>>(ei, cursor, col);

    // layer 1 (fp16 storage, fp32 linear); gat1: 4 edges/wave
    mm1_kernel<<<N_NODES / 8, 256, 0, stream>>>(x, Wl1, bl1, Wr1, br1, xl1, xr1);
    gat_node_kernel<64, 2><<<(N_NODES + 3) / 4, 256, 0, stream>>>(
        xl1, xr1, HO1, rowptr, col, att1, bias1, bn1g, bn1b, bn1m, bn1v, h1);

    // layer 2 (f16 MFMA GEMM, direct-to-LDS dbuf + r8-shape gat2)
    mm2_mfma_kernel<<<dim3(8, (N_NODES + 127) / 128), 256, 0, stream>>>(h1, Wt, bcat, xlr2);
    gat2_kernel<128><<<(N_NODES + 3) / 4, 256, 0, stream>>>(
        xlr2, xlr2 + HO2, 1024, rowptr, col, att2, bias2, bn2g, bn2b, bn2m, bn2v, h2b);

    // pool + head (separate: pooling needs high block-count TLP)
    pool_kernel<<<N_GRAPHS * 4, 256, 0, stream>>>(h2b, gs, pooled);
    mlp_kernel<<<N_GRAPHS, 128, 0, stream>>>(pooled, gf, fc1w, fc1b, fc2w, fc2b, out);
}

// Round 16
// 582.259 us; speedup vs baseline: 1.2852x; 1.1568x over previous
//
#include <hip/hip_runtime.h>

#define N_NODES 50000
#define N_EDGES 800000
#define N_GRAPHS 256
#define F_IN 9
#define GF_DIM 187
#define HO1 256
#define HO2 512
#define FC1_DIM 128
#define Z_DIM (HO2 + GF_DIM)   // 699

// ---------------- workspace layout (bytes) — proven footprint ----------------
#define OFF_XL1   0UL
#define OFF_XR1   25600000UL
#define OFF_XLR2  0UL
#define OFF_H1    102400000UL
#define OFF_H2    102400000UL
#define OFF_SMALL 153600000UL
#define OFF_DEG    (OFF_SMALL + 0UL)
#define OFF_ROWPTR (OFF_SMALL + 200704UL)
#define OFF_CURSOR (OFF_SMALL + 401408UL)
#define OFF_COL    (OFF_SMALL + 602112UL)
#define OFF_GS     (OFF_SMALL + 3802112UL)
#define OFF_POOLED (OFF_SMALL + 3806208UL)   // 512 KB fp32 pooled
#define OFF_WCAT   (OFF_SMALL + 4330496UL)
#define OFF_BCAT   (OFF_SMALL + 5379072UL)
#define WS_REQUIRED (OFF_SMALL + 5383168UL)   // 158,983,168 (proven)

typedef _Float16 half_t;
typedef __attribute__((ext_vector_type(2))) _Float16 h2;
typedef __attribute__((ext_vector_type(8))) _Float16 half8;   // f16 MFMA frag
typedef __attribute__((ext_vector_type(4))) float floatx4;

__device__ __forceinline__ h2 h2_bc(unsigned u) { return __builtin_bit_cast(h2, u); }
__device__ __forceinline__ unsigned u_bc(h2 v) { return __builtin_bit_cast(unsigned, v); }

// async global->LDS, 16B per lane; LDS dest = wave-uniform base + lane*16
__device__ __forceinline__ void gl2lds16(const half_t* g, half_t* l) {
    __builtin_amdgcn_global_load_lds((const __attribute__((address_space(1))) void*)g,
                                     (__attribute__((address_space(3))) void*)l,
                                     16, 0, 0);
}

// packed logit step over 4 words (8 halves): q += a06.(xs+xr) + a04.|xs+xr|
__device__ __forceinline__ float edge_logit_h(const unsigned* w, const h2* xr2,
                                              const h2* a06, const h2* a04,
                                              h2* xv2) {
    float q = 0.f;
#pragma unroll
    for (int i = 0; i < 4; ++i) {
        h2 xs = h2_bc(w[i]);
        xv2[i] = xs;
        h2 v = xs + xr2[i];                       // v_pk_add_f16
        q = __builtin_amdgcn_fdot2(a06[i], v, q, false);
        h2 va = h2_bc(u_bc(v) & 0x7fff7fffu);     // packed abs
        q = __builtin_amdgcn_fdot2(a04[i], va, q, false);
    }
    return q;
}

// ---------------- diagnostic fallback (ws too small) ----------------
__global__ void diag_kernel(float* out, float v) { out[threadIdx.x] = v; }

// ---------------- fused setup: zero deg | graph starts | pack W2 ----------------
__global__ __launch_bounds__(256) void setup_kernel(int* __restrict__ deg,
                                                    const int* __restrict__ batch,
                                                    int* __restrict__ gs,
                                                    const float* __restrict__ Wl2,
                                                    const float* __restrict__ Wr2,
                                                    const float* __restrict__ bl2,
                                                    const float* __restrict__ br2,
                                                    half_t* __restrict__ Wt,
                                                    float* __restrict__ bcat) {
    const int b = blockIdx.x, t = threadIdx.x;
    if (b < 196) {
        int i = b * 256 + t;
        if (i < N_NODES) deg[i] = 0;
    } else if (b == 196) {
        int lo = 0, hi = N_NODES;
        while (lo < hi) {
            int mid = (lo + hi) >> 1;
            if (batch[mid] < t) lo = mid + 1; else hi = mid;
        }
        gs[t] = lo;
        if (t == 0) gs[N_GRAPHS] = N_NODES;
    } else {
        int i = (b - 197) * 256 + t;          // 0 .. 1024*256-1
        int n = i >> 8, k = i & 255;
        float w = (n < HO2) ? Wl2[k * HO2 + n] : Wr2[k * HO2 + (n - HO2)];
        Wt[i] = (half_t)w;
        if (i < 1024) bcat[i] = (i < HO2) ? bl2[i] : br2[i - HO2];
    }
}

// ---------------- fused: layer-1 linear (blocks 0..6249) | edge count (6250..9374) --------
__global__ __launch_bounds__(256) void mm1_count_kernel(const float* __restrict__ x,
                                                        const float* __restrict__ Wl,
                                                        const float* __restrict__ bl,
                                                        const float* __restrict__ Wr,
                                                        const float* __restrict__ br,
                                                        half_t* __restrict__ xl,
                                                        half_t* __restrict__ xr,
                                                        const int* __restrict__ ei,
                                                        int* __restrict__ deg) {
    __shared__ float xs[8][F_IN];
    const int b = blockIdx.x, t = threadIdx.x;
    if (b >= N_NODES / 8) {           // count branch (3125 blocks)
        int e = (b - N_NODES / 8) * 256 + t;
        if (e < N_EDGES) atomicAdd(&deg[ei[N_EDGES + e]], 1);
        return;
    }
    const int n0 = b * 8;             // mm1 branch
    if (t < 8 * F_IN) xs[t / F_IN][t % F_IN] = x[n0 * F_IN + t];
    __syncthreads();
    const float blv = bl[t], brv = br[t];
    float sl[8], sr[8];
#pragma unroll
    for (int i = 0; i < 8; ++i) { sl[i] = blv; sr[i] = brv; }
#pragma unroll
    for (int k = 0; k < F_IN; ++k) {
        float wlk = Wl[k * HO1 + t];
        float wrk = Wr[k * HO1 + t];
#pragma unroll
        for (int i = 0; i < 8; ++i) {
            sl[i] = fmaf(xs[i][k], wlk, sl[i]);
            sr[i] = fmaf(xs[i][k], wrk, sr[i]);
        }
    }
#pragma unroll
    for (int i = 0; i < 8; ++i) {
        xl[(size_t)(n0 + i) * HO1 + t] = (half_t)sl[i];
        xr[(size_t)(n0 + i) * HO1 + t] = (half_t)sr[i];
    }
}

// ---------------- CSR scan (vectorized int4 loads/stores, 52 elems/thread) ----------------
__global__ __launch_bounds__(1024) void scan_kernel(const int* __restrict__ deg,
                                                    int* __restrict__ rowptr,
                                                    int* __restrict__ cursor) {
    __shared__ int part[1024];
    const int t = threadIdx.x;
    const int lo = t * 52;            // 16B-aligned chunks; 52*1024 = 53248 > N_NODES
    int d[52];
    int s = 0;
#pragma unroll
    for (int i = 0; i < 13; ++i) {    // overread past N_NODES stays inside ws; masked
        int4 v = *(const int4*)(deg + lo + 4 * i);
        int i0 = lo + 4 * i;
        d[4 * i + 0] = (i0 + 0 < N_NODES) ? v.x : 0;
        d[4 * i + 1] = (i0 + 1 < N_NODES) ? v.y : 0;
        d[4 * i + 2] = (i0 + 2 < N_NODES) ? v.z : 0;
        d[4 * i + 3] = (i0 + 3 < N_NODES) ? v.w : 0;
        s += d[4 * i] + d[4 * i + 1] + d[4 * i + 2] + d[4 * i + 3];
    }
    part[t] = s;
    __syncthreads();
    for (int off = 1; off < 1024; off <<= 1) {
        int v = (t >= off) ? part[t - off] : 0;
        __syncthreads();
        part[t] += v;
        __syncthreads();
    }
    int run = part[t] - s;  // exclusive base
#pragma unroll
    for (int i = 0; i < 13; ++i) {
        int i0 = lo + 4 * i;
        int4 r;
        r.x = run; run += d[4 * i + 0];
        r.y = run; run += d[4 * i + 1];
        r.z = run; run += d[4 * i + 2];
        r.w = run; run += d[4 * i + 3];
        if (i0 + 3 < N_NODES) {           // full vector in-bounds
            *(int4*)(rowptr + i0) = r;
            *(int4*)(cursor + i0) = r;
        } else {                          // masked scalar tail
            int rr[4] = {r.x, r.y, r.z, r.w};
#pragma unroll
            for (int j = 0; j < 4; ++j)
                if (i0 + j < N_NODES) { rowptr[i0 + j] = rr[j]; cursor[i0 + j] = rr[j]; }
        }
    }
    if (t == 1023) rowptr[N_NODES] = part[1023];
}

__global__ __launch_bounds__(256) void fill_kernel(const int* __restrict__ ei,
                                                   int* __restrict__ cursor,
                                                   int* __restrict__ col) {
    int e = blockIdx.x * 256 + threadIdx.x;
    if (e < N_EDGES) {
        int d = ei[N_EDGES + e];
        int pos = atomicAdd(&cursor[d], 1);
        col[pos] = ei[e];
    }
}

// ---------------- layer-2 linear: f16 MFMA, direct-to-LDS double-buffered ----------------
__global__ __launch_bounds__(256) void mm2_mfma_kernel(
    const half_t* __restrict__ A,    // h1 fp16 [N,256]
    const half_t* __restrict__ Bt,   // Wt fp16 [1024][256]
    const float* __restrict__ bias,  // bcat [1024]
    half_t* __restrict__ C) {        // xlr2 fp16 [N,1024]
    __shared__ half_t As[2][128 * 32];  // 2 x 8 KB
    __shared__ half_t Bs[2][128 * 32];  // 2 x 8 KB
    const int t = threadIdx.x;
    const int lane = t & 63;
    const int w = t >> 6;
    const int wr = w >> 1, wc = w & 1;       // wave quadrant (64x64)
    const int l15 = lane & 15, kq = lane >> 4;
    const int row0 = blockIdx.y * 128;
    const int col0 = blockIdx.x * 128;

    const int c1 = t, c2 = t + 256;
    int ar1 = row0 + (c1 >> 2); ar1 = ar1 < N_NODES ? ar1 : N_NODES - 1;
    int ar2 = row0 + (c2 >> 2); ar2 = ar2 < N_NODES ? ar2 : N_NODES - 1;
    const half_t* pa1 = A + (size_t)ar1 * 256 + (c1 & 3) * 8;
    const half_t* pa2 = A + (size_t)ar2 * 256 + (c2 & 3) * 8;
    const half_t* pb1 = Bt + (size_t)(col0 + (c1 >> 2)) * 256 + (c1 & 3) * 8;
    const half_t* pb2 = Bt + (size_t)(col0 + (c2 >> 2)) * 256 + (c2 & 3) * 8;
    const int l1 = c1 * 8;      // halves: byte offset t*16
    const int l2 = c2 * 8;

    gl2lds16(pa1, &As[0][l1]);
    gl2lds16(pa2, &As[0][l2]);
    gl2lds16(pb1, &Bs[0][l1]);
    gl2lds16(pb2, &Bs[0][l2]);

    floatx4 acc[4][4] = {};
    int buf = 0;
    for (int k0 = 0; k0 < 256; k0 += 32) {
        __syncthreads();             // drains vmcnt: LDS[buf] ready
        const bool more = (k0 + 32 < 256);
        if (more) {
            int nb = 1 - buf;
            gl2lds16(pa1 + k0 + 32, &As[nb][l1]);
            gl2lds16(pa2 + k0 + 32, &As[nb][l2]);
            gl2lds16(pb1 + k0 + 32, &Bs[nb][l1]);
            gl2lds16(pb2 + k0 + 32, &Bs[nb][l2]);
        }
        half8 af[4], bf[4];
#pragma unroll
        for (int i = 0; i < 4; ++i)
            af[i] = *(const half8*)&As[buf][(wr * 64 + i * 16 + l15) * 32 + kq * 8];
#pragma unroll
        for (int j = 0; j < 4; ++j)
            bf[j] = *(const half8*)&Bs[buf][(wc * 64 + j * 16 + l15) * 32 + kq * 8];
#pragma unroll
        for (int i = 0; i < 4; ++i)
#pragma unroll
            for (int j = 0; j < 4; ++j)
                acc[i][j] = __builtin_amdgcn_mfma_f32_16x16x32_f16(
                    af[i], bf[j], acc[i][j], 0, 0, 0);
        if (more) buf = 1 - buf;
    }
#pragma unroll
    for (int j = 0; j < 4; ++j) {
        int col = col0 + wc * 64 + j * 16 + l15;
        float bj = bias[col];
#pragma unroll
        for (int i = 0; i < 4; ++i) {
            int rbase = row0 + wr * 64 + i * 16 + kq * 4;
            floatx4 v = acc[i][j];
#pragma unroll
            for (int r = 0; r < 4; ++r) {
                int row = rbase + r;
                if (row < N_NODES) C[(size_t)row * 1024 + col] = (half_t)(v[r] + bj);
            }
        }
    }
}

// ---------------- gat1: GROUPS=2 lane-split, packed fp16 math (locked) ----------------
template <int O, int GROUPS>
__global__ __launch_bounds__(256, 4) void gat_node_kernel(
    const half_t* __restrict__ xl_, const half_t* __restrict__ xr_,
    int stride,
    const int* __restrict__ rowptr, const int* __restrict__ col,
    const float* __restrict__ att, const float* __restrict__ bias,
    const float* __restrict__ bng, const float* __restrict__ bnb,
    const float* __restrict__ bnm, const float* __restrict__ bnv,
    half_t* __restrict__ out_) {
    constexpr int TOT = 4 * O;
    constexpr int GS  = 64 / GROUPS;
    constexpr int VE  = TOT / GS;     // 8
    constexpr int LPH = O / VE;
    const int wave = threadIdx.x >> 6;
    const int node = blockIdx.x * 4 + wave;
    if (node >= N_NODES) return;
    const int lane = threadIdx.x & 63;
    const int gid  = lane / GS;
    const int gl   = lane % GS;
    const int cbase = gl * VE;

    h2 xr2[4], a06[4], a04[4], acc2[4], xvA[4], xvB[4];
    {
        uint4 q = *(const uint4*)(xr_ + (size_t)node * stride + cbase);
        xr2[0] = h2_bc(q.x); xr2[1] = h2_bc(q.y);
        xr2[2] = h2_bc(q.z); xr2[3] = h2_bc(q.w);
#pragma unroll
        for (int v = 0; v < VE; v += 4) {
            float4 b = *(const float4*)(att + cbase + v);
            a06[v / 2]     = h2{(half_t)(0.6f * b.x), (half_t)(0.6f * b.y)};
            a06[v / 2 + 1] = h2{(half_t)(0.6f * b.z), (half_t)(0.6f * b.w)};
            a04[v / 2]     = h2{(half_t)(0.4f * b.x), (half_t)(0.4f * b.y)};
            a04[v / 2 + 1] = h2{(half_t)(0.4f * b.z), (half_t)(0.4f * b.w)};
        }
    }
    float s;
    {
        unsigned w_[4];
        *(uint4*)w_ = *(const uint4*)(xl_ + (size_t)node * stride + cbase);
        float q = edge_logit_h(w_, xr2, a06, a04, xvA);
#pragma unroll
        for (int d = 1; d < LPH; d <<= 1) q += __shfl_xor(q, d, 64);
        float w0 = (GROUPS == 1 || gid == 0) ? __expf(q) : 0.f;
        s = w0;
        h2 w0h = h2{(half_t)w0, (half_t)w0};
#pragma unroll
        for (int j = 0; j < 4; ++j) acc2[j] = w0h * xvA[j];
    }

    const int e0 = rowptr[node], e1 = rowptr[node + 1];
    const int deg = e1 - e0;
    constexpr int PER = 2 * GROUPS;
    const int itc = (deg + PER - 1) / PER;
    const int elast = e1 - 1;
    int ia = e0 + 2 * gid;
    unsigned nA[4], nB[4];
    if (itc > 0) {
        int a = ia < elast ? ia : elast;
        int b = ia + 1 < elast ? ia + 1 : elast;
        *(uint4*)nA = *(const uint4*)(xl_ + (size_t)col[a] * stride + cbase);
        *(uint4*)nB = *(const uint4*)(xl_ + (size_t)col[b] * stride + cbase);
    }
    for (int k = 0; k < itc; ++k) {
        unsigned cA[4], cB[4];
#pragma unroll
        for (int i = 0; i < 4; ++i) { cA[i] = nA[i]; cB[i] = nB[i]; }
        int inext = ia + PER;
        if (k + 1 < itc) {
            int a = inext < elast ? inext : elast;
            int b = inext + 1 < elast ? inext + 1 : elast;
            *(uint4*)nA = *(const uint4*)(xl_ + (size_t)col[a] * stride + cbase);
            *(uint4*)nB = *(const uint4*)(xl_ + (size_t)col[b] * stride + cbase);
        }
        float q1 = edge_logit_h(cA, xr2, a06, a04, xvA);
        float q2 = edge_logit_h(cB, xr2, a06, a04, xvB);
#pragma unroll
        for (int d = 1; d < LPH; d <<= 1) {
            q1 += __shfl_xor(q1, d, 64);
            q2 += __shfl_xor(q2, d, 64);
        }
        float w1 = (ia < e1) ? __expf(q1) : 0.f;
        float w2 = (ia + 1 < e1) ? __expf(q2) : 0.f;
        s += w1 + w2;
        h2 w1h = h2{(half_t)w1, (half_t)w1};
        h2 w2h = h2{(half_t)w2, (half_t)w2};
#pragma unroll
        for (int j = 0; j < 4; ++j)
            acc2[j] += w1h * xvA[j] + w2h * xvB[j];
        ia = inext;
    }
    if constexpr (GROUPS == 2) {
        s += __shfl_xor(s, 32, 64);
#pragma unroll
        for (int j = 0; j < 4; ++j) {
            float tmp = __builtin_bit_cast(float, acc2[j]);
            float o = __shfl_xor(tmp, 32, 64);
            acc2[j] += __builtin_bit_cast(h2, o);
        }
    }
    float r = 1.f / (s + 1e-16f);
    if (GROUPS == 1 || gid == 0) {
        half_t t[8];
#pragma unroll
        for (int j = 0; j < 4; ++j) {
#pragma unroll
            for (int p = 0; p < 2; ++p) {
                int c = cbase + 2 * j + p;
                float val = (float)acc2[j][p] * r + bias[c];
                float y = bng[c] * (val - bnm[c]) * rsqrtf(bnv[c] + 1e-5f) + bnb[c];
                t[2 * j + p] = (half_t)fmaxf(y, 0.f);
            }
        }
        uint4 qo;
        qo.x = u_bc(h2{t[0], t[1]});
        qo.y = u_bc(h2{t[2], t[3]});
        qo.z = u_bc(h2{t[4], t[5]});
        qo.w = u_bc(h2{t[6], t[7]});
        *(uint4*)(out_ + (size_t)node * TOT + cbase) = qo;
    }
}

// ---------------- gat2: r8-exact loop shape, packed fp16 math (locked) ----------------
template <int O>
__global__ __launch_bounds__(256, 4) void gat2_kernel(
    const half_t* __restrict__ xl_, const half_t* __restrict__ xr_,
    int stride,
    const int* __restrict__ rowptr, const int* __restrict__ col,
    const float* __restrict__ att, const float* __restrict__ bias,
    const float* __restrict__ bng, const float* __restrict__ bnb,
    const float* __restrict__ bnm, const float* __restrict__ bnv,
    half_t* __restrict__ out_) {
    constexpr int VE = O / 16;        // 8
    constexpr int HO = 4 * O;
    const int wave = threadIdx.x >> 6;
    const int node = blockIdx.x * 4 + wave;
    if (node >= N_NODES) return;
    const int lane = threadIdx.x & 63;
    const int l16 = lane & 15;
    const int cbase = (lane >> 4) * O + l16 * VE;

    h2 xr2[4], a06[4], a04[4], acc2[4], xvA[4], xvB[4];
    {
        uint4 q = *(const uint4*)(xr_ + (size_t)node * stride + cbase);
        xr2[0] = h2_bc(q.x); xr2[1] = h2_bc(q.y);
        xr2[2] = h2_bc(q.z); xr2[3] = h2_bc(q.w);
#pragma unroll
        for (int v = 0; v < VE; v += 4) {
            float4 b = *(const float4*)(att + cbase + v);
            a06[v / 2]     = h2{(half_t)(0.6f * b.x), (half_t)(0.6f * b.y)};
            a06[v / 2 + 1] = h2{(half_t)(0.6f * b.z), (half_t)(0.6f * b.w)};
            a04[v / 2]     = h2{(half_t)(0.4f * b.x), (half_t)(0.4f * b.y)};
            a04[v / 2 + 1] = h2{(half_t)(0.4f * b.z), (half_t)(0.4f * b.w)};
        }
    }
    float s;
    {
        unsigned ws_[4];
        *(uint4*)ws_ = *(const uint4*)(xl_ + (size_t)node * stride + cbase);
        float q = edge_logit_h(ws_, xr2, a06, a04, xvA);
#pragma unroll
        for (int d = 1; d < 16; d <<= 1) q += __shfl_xor(q, d, 64);
        float w0 = __expf(q);
        s = w0;
        h2 w0h = h2{(half_t)w0, (half_t)w0};
#pragma unroll
        for (int j = 0; j < 4; ++j) acc2[j] = w0h * xvA[j];
    }

    int e = rowptr[node];
    const int e1 = rowptr[node + 1];
    const int elast = e1 - 1;
    unsigned nA[4], nB[4];
    if (e < e1) *(uint4*)nA = *(const uint4*)(xl_ + (size_t)col[e] * stride + cbase);
    if (e + 1 < e1) *(uint4*)nB = *(const uint4*)(xl_ + (size_t)col[e + 1] * stride + cbase);
    while (e + 1 < e1) {
        unsigned cA[4], cB[4];
#pragma unroll
        for (int i = 0; i < 4; ++i) { cA[i] = nA[i]; cB[i] = nB[i]; }
        int i2 = e + 2 < elast ? e + 2 : elast;
        int i3 = e + 3 < elast ? e + 3 : elast;
        *(uint4*)nA = *(const uint4*)(xl_ + (size_t)col[i2] * stride + cbase);
        *(uint4*)nB = *(const uint4*)(xl_ + (size_t)col[i3] * stride + cbase);
        e += 2;
        float q1 = edge_logit_h(cA, xr2, a06, a04, xvA);
        float q2 = edge_logit_h(cB, xr2, a06, a04, xvB);
#pragma unroll
        for (int d = 1; d < 16; d <<= 1) {
            q1 += __shfl_xor(q1, d, 64);
            q2 += __shfl_xor(q2, d, 64);
        }
        float w1 = __expf(q1), w2 = __expf(q2);
        s += w1 + w2;
        h2 w1h = h2{(half_t)w1, (half_t)w1};
        h2 w2h = h2{(half_t)w2, (half_t)w2};
#pragma unroll
        for (int j = 0; j < 4; ++j)
            acc2[j] += w1h * xvA[j] + w2h * xvB[j];
    }
    if (e < e1) {
        float q = edge_logit_h(nA, xr2, a06, a04, xvA);
#pragma unroll
        for (int d = 1; d < 16; d <<= 1) q += __shfl_xor(q, d, 64);
        float we = __expf(q);
        s += we;
        h2 weh = h2{(half_t)we, (half_t)we};
#pragma unroll
        for (int j = 0; j < 4; ++j) acc2[j] += weh * xvA[j];
    }
    float r = 1.f / (s + 1e-16f);
    half_t t[8];
#pragma unroll
    for (int j = 0; j < 4; ++j) {
#pragma unroll
        for (int p = 0; p < 2; ++p) {
            int c = cbase + 2 * j + p;
            float val = (float)acc2[j][p] * r + bias[c];
            float y = bng[c] * (val - bnm[c]) * rsqrtf(bnv[c] + 1e-5f) + bnb[c];
            t[2 * j + p] = (half_t)fmaxf(y, 0.f);
        }
    }
    uint4 qo;
    qo.x = u_bc(h2{t[0], t[1]});
    qo.y = u_bc(h2{t[2], t[3]});
    qo.z = u_bc(h2{t[4], t[5]});
    qo.w = u_bc(h2{t[6], t[7]});
    *(uint4*)(out_ + (size_t)node * HO + cbase) = qo;
}

// ---------------- mean pool: 4 blocks/graph x 4 row-stripes (high TLP) ----------------
__global__ __launch_bounds__(256) void pool_kernel(const half_t* __restrict__ hb,
                                                   const int* __restrict__ gs,
                                                   float* __restrict__ pooled) {
    __shared__ float red[4][128];
    const int g = blockIdx.x >> 2;
    const int q = blockIdx.x & 3;
    const int t = threadIdx.x;
    const int p = t >> 6, w = t & 63;
    const int s = gs[g], e = gs[g + 1];
    const half_t* base = hb + q * 128 + w * 2;
    float a0 = 0.f, a1 = 0.f;
    for (int r = s + p; r < e; r += 4) {
        unsigned u = *(const unsigned*)(base + (size_t)r * HO2);
        h2 v = h2_bc(u);
        a0 += (float)v[0];
        a1 += (float)v[1];
    }
    red[p][w * 2] = a0;
    red[p][w * 2 + 1] = a1;
    __syncthreads();
    if (p == 0) {
        float inv = 1.f / fmaxf((float)(e - s), 1.f);
        float v0 = (red[0][w * 2] + red[1][w * 2] + red[2][w * 2] + red[3][w * 2]) * inv;
        float v1 = (red[0][w * 2 + 1] + red[1][w * 2 + 1] + red[2][w * 2 + 1] + red[3][w * 2 + 1]) * inv;
        float2 o; o.x = v0; o.y = v1;
        *(float2*)(pooled + (size_t)g * HO2 + q * 128 + w * 2) = o;
    }
}

// ---------------- MLP head ----------------
__global__ __launch_bounds__(128) void mlp_kernel(const float* __restrict__ pooled,
                                                  const float* __restrict__ gf,
                                                  const float* __restrict__ fc1w,
                                                  const float* __restrict__ fc1b,
                                                  const float* __restrict__ fc2w,
                                                  const float* __restrict__ fc2b,
                                                  float* __restrict__ out) {
    __shared__ float z[704];
    __shared__ float red[2];
    const int g = blockIdx.x, t = threadIdx.x;
    for (int i = t; i < HO2; i += 128) z[i] = pooled[(size_t)g * HO2 + i];
    for (int i = t; i < GF_DIM; i += 128) z[HO2 + i] = gf[(size_t)g * GF_DIM + i];
    __syncthreads();
    float s = fc1b[t];
    for (int k = 0; k < Z_DIM; ++k) s += z[k] * fc1w[k * FC1_DIM + t];
    s = fmaxf(s, 0.f);              // relu (dropout = identity in eval)
    float c = s * fc2w[t];
#pragma unroll
    for (int d = 1; d < 64; d <<= 1) c += __shfl_xor(c, d, 64);
    if ((t & 63) == 0) red[t >> 6] = c;
    __syncthreads();
    if (t == 0) out[g] = red[0] + red[1] + fc2b[0];
}

// ---------------- launch ----------------
extern "C" void kernel_launch(void* const* d_in, const int* in_sizes, int n_in,
                              void* d_out, int out_size, void* d_ws, size_t ws_size,
                              hipStream_t stream) {
    float* out = (float*)d_out;
    if (ws_size < WS_REQUIRED) {
        diag_kernel<<<1, 256, 0, stream>>>(out, (float)(ws_size >> 20));
        return;
    }
    const float* x     = (const float*)d_in[0];
    const int*   ei    = (const int*)d_in[1];
    const int*   batch = (const int*)d_in[2];
    const float* gf    = (const float*)d_in[3];
    const float* Wl1   = (const float*)d_in[4];
    const float* bl1   = (const float*)d_in[5];
    const float* Wr1   = (const float*)d_in[6];
    const float* br1   = (const float*)d_in[7];
    const float* att1  = (const float*)d_in[8];
    const float* bias1 = (const float*)d_in[9];
    const float* bn1g  = (const float*)d_in[10];
    const float* bn1b  = (const float*)d_in[11];
    const float* bn1m  = (const float*)d_in[12];
    const float* bn1v  = (const float*)d_in[13];
    const float* Wl2   = (const float*)d_in[14];
    const float* bl2   = (const float*)d_in[15];
    const float* Wr2   = (const float*)d_in[16];
    const float* br2   = (const float*)d_in[17];
    const float* att2  = (const float*)d_in[18];
    const float* bias2 = (const float*)d_in[19];
    const float* bn2g  = (const float*)d_in[20];
    const float* bn2b  = (const float*)d_in[21];
    const float* bn2m  = (const float*)d_in[22];
    const float* bn2v  = (const float*)d_in[23];
    const float* fc1w  = (const float*)d_in[24];
    const float* fc1b  = (const float*)d_in[25];
    const float* fc2w  = (const float*)d_in[26];
    const float* fc2b  = (const float*)d_in[27];
    char* ws = (char*)d_ws;

    half_t* xl1  = (half_t*)(ws + OFF_XL1);
    half_t* xr1  = (half_t*)(ws + OFF_XR1);
    half_t* xlr2 = (half_t*)(ws + OFF_XLR2);
    half_t* h1   = (half_t*)(ws + OFF_H1);
    half_t* h2b  = (half_t*)(ws + OFF_H2);
    int* deg     = (int*)(ws + OFF_DEG);
    int* rowptr  = (int*)(ws + OFF_ROWPTR);
    int* cursor  = (int*)(ws + OFF_CURSOR);
    int* col     = (int*)(ws + OFF_COL);
    int* gs      = (int*)(ws + OFF_GS);
    float* pooled= (float*)(ws + OFF_POOLED);
    half_t* Wt   = (half_t*)(ws + OFF_WCAT);
    float* bcat  = (float*)(ws + OFF_BCAT);

    // setup (zero deg | gstart | pack W2) -> [mm1 || count] -> scan -> fill
    setup_kernel<<<1221, 256, 0, stream>>>(deg, batch, gs, Wl2, Wr2, bl2, br2, Wt, bcat);
    mm1_count_kernel<<<N_NODES / 8 + N_EDGES / 256, 256, 0, stream>>>(
        x, Wl1, bl1, Wr1, br1, xl1, xr1, ei, deg);
    scan_kernel<<<1, 1024, 0, stream>>>(deg, rowptr, cursor);
    fill_kernel<<<(N_EDGES + 255) / 256, 256, 0, stream>>>(ei, cursor, col);

    // layer 1 gather (fp16, 4 edges/wave)
    gat_node_kernel<64, 2><<<(N_NODES + 3) / 4, 256, 0, stream>>>(
        xl1, xr1, HO1, rowptr, col, att1, bias1, bn1g, bn1b, bn1m, bn1v, h1);

    // layer 2 (f16 MFMA GEMM, direct-to-LDS dbuf + r8-shape gat2)
    mm2_mfma_kernel<<<dim3(8, (N_NODES + 127) / 128), 256, 0, stream>>>(h1, Wt, bcat, xlr2);
    gat2_kernel<128><<<(N_NODES + 3) / 4, 256, 0, stream>>>(
        xlr2, xlr2 + HO2, 1024, rowptr, col, att2, bias2, bn2g, bn2b, bn2m, bn2v, h2b);

    // pool + head
    pool_kernel<<<N_GRAPHS * 4, 256, 0, stream>>>(h2b, gs, pooled);
    mlp_kernel<<<N_GRAPHS, 128, 0, stream>>>(pooled, gf, fc1w, fc1b, fc2w, fc2b, out);
}

// Round 17
// 580.252 us; speedup vs baseline: 1.2897x; 1.0035x over previous
//
#include <hip/hip_runtime.h>

#define N_NODES 50000
#define N_EDGES 800000
#define N_GRAPHS 256
#define F_IN 9
#define GF_DIM 187
#define HO1 256
#define HO2 512
#define FC1_DIM 128
#define Z_DIM (HO2 + GF_DIM)   // 699

// ---------------- workspace layout (bytes) — proven footprint ----------------
#define OFF_XL1   0UL
#define OFF_XR1   25600000UL
#define OFF_XLR2  0UL
#define OFF_H1    102400000UL
#define OFF_H2    102400000UL
#define OFF_SMALL 153600000UL
#define OFF_DEG    (OFF_SMALL + 0UL)
#define OFF_ROWPTR (OFF_SMALL + 200704UL)
#define OFF_CURSOR (OFF_SMALL + 401408UL)
#define OFF_COL    (OFF_SMALL + 602112UL)
#define OFF_GS     (OFF_SMALL + 3802112UL)
#define OFF_POOLED (OFF_SMALL + 3806208UL)   // 512 KB fp32 pooled
#define OFF_WCAT   (OFF_SMALL + 4330496UL)
#define OFF_BCAT   (OFF_SMALL + 5379072UL)
#define WS_REQUIRED (OFF_SMALL + 5383168UL)   // 158,983,168 (proven)

typedef _Float16 half_t;
typedef __attribute__((ext_vector_type(2))) _Float16 h2;
typedef __attribute__((ext_vector_type(8))) _Float16 half8;   // f16 MFMA frag
typedef __attribute__((ext_vector_type(4))) float floatx4;

__device__ __forceinline__ h2 h2_bc(unsigned u) { return __builtin_bit_cast(h2, u); }
__device__ __forceinline__ unsigned u_bc(h2 v) { return __builtin_bit_cast(unsigned, v); }

// async global->LDS, 16B per lane; LDS dest = wave-uniform base + lane*16
__device__ __forceinline__ void gl2lds16(const half_t* g, half_t* l) {
    __builtin_amdgcn_global_load_lds((const __attribute__((address_space(1))) void*)g,
                                     (__attribute__((address_space(3))) void*)l,
                                     16, 0, 0);
}

// packed logit step over 4 words (8 halves): q += a06.(xs+xr) + a04.|xs+xr|
__device__ __forceinline__ float edge_logit_h(const unsigned* w, const h2* xr2,
                                              const h2* a06, const h2* a04,
                                              h2* xv2) {
    float q = 0.f;
#pragma unroll
    for (int i = 0; i < 4; ++i) {
        h2 xs = h2_bc(w[i]);
        xv2[i] = xs;
        h2 v = xs + xr2[i];                       // v_pk_add_f16
        q = __builtin_amdgcn_fdot2(a06[i], v, q, false);
        h2 va = h2_bc(u_bc(v) & 0x7fff7fffu);     // packed abs
        q = __builtin_amdgcn_fdot2(a04[i], va, q, false);
    }
    return q;
}

// ---------------- diagnostic fallback (ws too small) ----------------
__global__ void diag_kernel(float* out, float v) { out[threadIdx.x] = v; }

// ---------------- fused setup: zero deg | graph starts | pack W2 ----------------
__global__ __launch_bounds__(256) void setup_kernel(int* __restrict__ deg,
                                                    const int* __restrict__ batch,
                                                    int* __restrict__ gs,
                                                    const float* __restrict__ Wl2,
                                                    const float* __restrict__ Wr2,
                                                    const float* __restrict__ bl2,
                                                    const float* __restrict__ br2,
                                                    half_t* __restrict__ Wt,
                                                    float* __restrict__ bcat) {
    const int b = blockIdx.x, t = threadIdx.x;
    if (b < 196) {
        int i = b * 256 + t;
        if (i < N_NODES) deg[i] = 0;
    } else if (b == 196) {
        int lo = 0, hi = N_NODES;
        while (lo < hi) {
            int mid = (lo + hi) >> 1;
            if (batch[mid] < t) lo = mid + 1; else hi = mid;
        }
        gs[t] = lo;
        if (t == 0) gs[N_GRAPHS] = N_NODES;
    } else {
        int i = (b - 197) * 256 + t;          // 0 .. 1024*256-1
        int n = i >> 8, k = i & 255;
        float w = (n < HO2) ? Wl2[k * HO2 + n] : Wr2[k * HO2 + (n - HO2)];
        Wt[i] = (half_t)w;
        if (i < 1024) bcat[i] = (i < HO2) ? bl2[i] : br2[i - HO2];
    }
}

// ---------------- fused: layer-1 linear (blocks 0..6249) | edge count (6250..9374) --------
__global__ __launch_bounds__(256) void mm1_count_kernel(const float* __restrict__ x,
                                                        const float* __restrict__ Wl,
                                                        const float* __restrict__ bl,
                                                        const float* __restrict__ Wr,
                                                        const float* __restrict__ br,
                                                        half_t* __restrict__ xl,
                                                        half_t* __restrict__ xr,
                                                        const int* __restrict__ ei,
                                                        int* __restrict__ deg) {
    __shared__ float xs[8][F_IN];
    const int b = blockIdx.x, t = threadIdx.x;
    if (b >= N_NODES / 8) {           // count branch (3125 blocks)
        int e = (b - N_NODES / 8) * 256 + t;
        if (e < N_EDGES) atomicAdd(&deg[ei[N_EDGES + e]], 1);
        return;
    }
    const int n0 = b * 8;             // mm1 branch
    if (t < 8 * F_IN) xs[t / F_IN][t % F_IN] = x[n0 * F_IN + t];
    __syncthreads();
    const float blv = bl[t], brv = br[t];
    float sl[8], sr[8];
#pragma unroll
    for (int i = 0; i < 8; ++i) { sl[i] = blv; sr[i] = brv; }
#pragma unroll
    for (int k = 0; k < F_IN; ++k) {
        float wlk = Wl[k * HO1 + t];
        float wrk = Wr[k * HO1 + t];
#pragma unroll
        for (int i = 0; i < 8; ++i) {
            sl[i] = fmaf(xs[i][k], wlk, sl[i]);
            sr[i] = fmaf(xs[i][k], wrk, sr[i]);
        }
    }
#pragma unroll
    for (int i = 0; i < 8; ++i) {
        xl[(size_t)(n0 + i) * HO1 + t] = (half_t)sl[i];
        xr[(size_t)(n0 + i) * HO1 + t] = (half_t)sr[i];
    }
}

// ---------------- CSR scan (vectorized int4 loads/stores, 52 elems/thread) ----------------
__global__ __launch_bounds__(1024) void scan_kernel(const int* __restrict__ deg,
                                                    int* __restrict__ rowptr,
                                                    int* __restrict__ cursor) {
    __shared__ int part[1024];
    const int t = threadIdx.x;
    const int lo = t * 52;            // 16B-aligned chunks; 52*1024 = 53248 > N_NODES
    int d[52];
    int s = 0;
#pragma unroll
    for (int i = 0; i < 13; ++i) {    // overread past N_NODES stays inside ws; masked
        int4 v = *(const int4*)(deg + lo + 4 * i);
        int i0 = lo + 4 * i;
        d[4 * i + 0] = (i0 + 0 < N_NODES) ? v.x : 0;
        d[4 * i + 1] = (i0 + 1 < N_NODES) ? v.y : 0;
        d[4 * i + 2] = (i0 + 2 < N_NODES) ? v.z : 0;
        d[4 * i + 3] = (i0 + 3 < N_NODES) ? v.w : 0;
        s += d[4 * i] + d[4 * i + 1] + d[4 * i + 2] + d[4 * i + 3];
    }
    part[t] = s;
    __syncthreads();
    for (int off = 1; off < 1024; off <<= 1) {
        int v = (t >= off) ? part[t - off] : 0;
        __syncthreads();
        part[t] += v;
        __syncthreads();
    }
    int run = part[t] - s;  // exclusive base
#pragma unroll
    for (int i = 0; i < 13; ++i) {
        int i0 = lo + 4 * i;
        int4 r;
        r.x = run; run += d[4 * i + 0];
        r.y = run; run += d[4 * i + 1];
        r.z = run; run += d[4 * i + 2];
        r.w = run; run += d[4 * i + 3];
        if (i0 + 3 < N_NODES) {           // full vector in-bounds
            *(int4*)(rowptr + i0) = r;
            *(int4*)(cursor + i0) = r;
        } else {                          // masked scalar tail
            int rr[4] = {r.x, r.y, r.z, r.w};
#pragma unroll
            for (int j = 0; j < 4; ++j)
                if (i0 + j < N_NODES) { rowptr[i0 + j] = rr[j]; cursor[i0 + j] = rr[j]; }
        }
    }
    if (t == 1023) rowptr[N_NODES] = part[1023];
}

__global__ __launch_bounds__(256) void fill_kernel(const int* __restrict__ ei,
                                                   int* __restrict__ cursor,
                                                   int* __restrict__ col) {
    int e = blockIdx.x * 256 + threadIdx.x;
    if (e < N_EDGES) {
        int d = ei[N_EDGES + e];
        int pos = atomicAdd(&cursor[d], 1);
        col[pos] = ei[e];
    }
}

// ---------------- layer-2 linear: f16 MFMA, direct-to-LDS double-buffered ----------------
__global__ __launch_bounds__(256) void mm2_mfma_kernel(
    const half_t* __restrict__ A,    // h1 fp16 [N,256]
    const half_t* __restrict__ Bt,   // Wt fp16 [1024][256]
    const float* __restrict__ bias,  // bcat [1024]
    half_t* __restrict__ C) {        // xlr2 fp16 [N,1024]
    __shared__ half_t As[2][128 * 32];  // 2 x 8 KB
    __shared__ half_t Bs[2][128 * 32];  // 2 x 8 KB
    const int t = threadIdx.x;
    const int lane = t & 63;
    const int w = t >> 6;
    const int wr = w >> 1, wc = w & 1;       // wave quadrant (64x64)
    const int l15 = lane & 15, kq = lane >> 4;
    const int row0 = blockIdx.y * 128;
    const int col0 = blockIdx.x * 128;

    const int c1 = t, c2 = t + 256;
    int ar1 = row0 + (c1 >> 2); ar1 = ar1 < N_NODES ? ar1 : N_NODES - 1;
    int ar2 = row0 + (c2 >> 2); ar2 = ar2 < N_NODES ? ar2 : N_NODES - 1;
    const half_t* pa1 = A + (size_t)ar1 * 256 + (c1 & 3) * 8;
    const half_t* pa2 = A + (size_t)ar2 * 256 + (c2 & 3) * 8;
    const half_t* pb1 = Bt + (size_t)(col0 + (c1 >> 2)) * 256 + (c1 & 3) * 8;
    const half_t* pb2 = Bt + (size_t)(col0 + (c2 >> 2)) * 256 + (c2 & 3) * 8;
    const int l1 = c1 * 8;      // halves: byte offset t*16
    const int l2 = c2 * 8;

    gl2lds16(pa1, &As[0][l1]);
    gl2lds16(pa2, &As[0][l2]);
    gl2lds16(pb1, &Bs[0][l1]);
    gl2lds16(pb2, &Bs[0][l2]);

    floatx4 acc[4][4] = {};
    int buf = 0;
    for (int k0 = 0; k0 < 256; k0 += 32) {
        __syncthreads();             // drains vmcnt: LDS[buf] ready
        const bool more = (k0 + 32 < 256);
        if (more) {
            int nb = 1 - buf;
            gl2lds16(pa1 + k0 + 32, &As[nb][l1]);
            gl2lds16(pa2 + k0 + 32, &As[nb][l2]);
            gl2lds16(pb1 + k0 + 32, &Bs[nb][l1]);
            gl2lds16(pb2 + k0 + 32, &Bs[nb][l2]);
        }
        half8 af[4], bf[4];
#pragma unroll
        for (int i = 0; i < 4; ++i)
            af[i] = *(const half8*)&As[buf][(wr * 64 + i * 16 + l15) * 32 + kq * 8];
#pragma unroll
        for (int j = 0; j < 4; ++j)
            bf[j] = *(const half8*)&Bs[buf][(wc * 64 + j * 16 + l15) * 32 + kq * 8];
#pragma unroll
        for (int i = 0; i < 4; ++i)
#pragma unroll
            for (int j = 0; j < 4; ++j)
                acc[i][j] = __builtin_amdgcn_mfma_f32_16x16x32_f16(
                    af[i], bf[j], acc[i][j], 0, 0, 0);
        if (more) buf = 1 - buf;
    }
#pragma unroll
    for (int j = 0; j < 4; ++j) {
        int col = col0 + wc * 64 + j * 16 + l15;
        float bj = bias[col];
#pragma unroll
        for (int i = 0; i < 4; ++i) {
            int rbase = row0 + wr * 64 + i * 16 + kq * 4;
            floatx4 v = acc[i][j];
#pragma unroll
            for (int r = 0; r < 4; ++r) {
                int row = rbase + r;
                if (row < N_NODES) C[(size_t)row * 1024 + col] = (half_t)(v[r] + bj);
            }
        }
    }
}

// ---------------- gat1: GROUPS=2 lane-split, fp16, ring-2 prefetch ----------------
template <int O, int GROUPS>
__global__ __launch_bounds__(256, 4) void gat_node_kernel(
    const half_t* __restrict__ xl_, const half_t* __restrict__ xr_,
    int stride,
    const int* __restrict__ rowptr, const int* __restrict__ col,
    const float* __restrict__ att, const float* __restrict__ bias,
    const float* __restrict__ bng, const float* __restrict__ bnb,
    const float* __restrict__ bnm, const float* __restrict__ bnv,
    half_t* __restrict__ out_) {
    constexpr int TOT = 4 * O;
    constexpr int GS  = 64 / GROUPS;
    constexpr int VE  = TOT / GS;     // 8
    constexpr int LPH = O / VE;
    const int wave = threadIdx.x >> 6;
    const int node = blockIdx.x * 4 + wave;
    if (node >= N_NODES) return;
    const int lane = threadIdx.x & 63;
    const int gid  = lane / GS;
    const int gl   = lane % GS;
    const int cbase = gl * VE;

    h2 xr2[4], a06[4], a04[4], acc2[4], xvA[4], xvB[4];
    {
        uint4 q = *(const uint4*)(xr_ + (size_t)node * stride + cbase);
        xr2[0] = h2_bc(q.x); xr2[1] = h2_bc(q.y);
        xr2[2] = h2_bc(q.z); xr2[3] = h2_bc(q.w);
#pragma unroll
        for (int v = 0; v < VE; v += 4) {
            float4 b = *(const float4*)(att + cbase + v);
            a06[v / 2]     = h2{(half_t)(0.6f * b.x), (half_t)(0.6f * b.y)};
            a06[v / 2 + 1] = h2{(half_t)(0.6f * b.z), (half_t)(0.6f * b.w)};
            a04[v / 2]     = h2{(half_t)(0.4f * b.x), (half_t)(0.4f * b.y)};
            a04[v / 2 + 1] = h2{(half_t)(0.4f * b.z), (half_t)(0.4f * b.w)};
        }
    }
    float s;
    {
        unsigned w_[4];
        *(uint4*)w_ = *(const uint4*)(xl_ + (size_t)node * stride + cbase);
        float q = edge_logit_h(w_, xr2, a06, a04, xvA);
#pragma unroll
        for (int d = 1; d < LPH; d <<= 1) q += __shfl_xor(q, d, 64);
        float w0 = (GROUPS == 1 || gid == 0) ? __expf(q) : 0.f;
        s = w0;
        h2 w0h = h2{(half_t)w0, (half_t)w0};
#pragma unroll
        for (int j = 0; j < 4; ++j) acc2[j] = w0h * xvA[j];
    }

    const int e0 = rowptr[node], e1 = rowptr[node + 1];
    const int deg = e1 - e0;
    constexpr int PER = 2 * GROUPS;
    const int itc = (deg + PER - 1) / PER;
    const int elast = e1 - 1;
    int ia = e0 + 2 * gid;
    unsigned nA[4], nB[4], mA[4], mB[4];
    if (itc > 0) {
        int a = ia < elast ? ia : elast;
        int b = ia + 1 < elast ? ia + 1 : elast;
        *(uint4*)nA = *(const uint4*)(xl_ + (size_t)col[a] * stride + cbase);
        *(uint4*)nB = *(const uint4*)(xl_ + (size_t)col[b] * stride + cbase);
    }
    if (itc > 1) {
        int a = ia + PER < elast ? ia + PER : elast;
        int b = ia + PER + 1 < elast ? ia + PER + 1 : elast;
        *(uint4*)mA = *(const uint4*)(xl_ + (size_t)col[a] * stride + cbase);
        *(uint4*)mB = *(const uint4*)(xl_ + (size_t)col[b] * stride + cbase);
    }
    for (int k = 0; k < itc; ++k) {
        unsigned cA[4], cB[4];
#pragma unroll
        for (int i = 0; i < 4; ++i) {
            cA[i] = nA[i]; cB[i] = nB[i];
            nA[i] = mA[i]; nB[i] = mB[i];
        }
        if (k + 2 < itc) {                    // ring-2: prefetch pair k+2
            int p = ia + 2 * PER;
            int a = p < elast ? p : elast;
            int b = p + 1 < elast ? p + 1 : elast;
            *(uint4*)mA = *(const uint4*)(xl_ + (size_t)col[a] * stride + cbase);
            *(uint4*)mB = *(const uint4*)(xl_ + (size_t)col[b] * stride + cbase);
        }
        float q1 = edge_logit_h(cA, xr2, a06, a04, xvA);
        float q2 = edge_logit_h(cB, xr2, a06, a04, xvB);
#pragma unroll
        for (int d = 1; d < LPH; d <<= 1) {
            q1 += __shfl_xor(q1, d, 64);
            q2 += __shfl_xor(q2, d, 64);
        }
        float w1 = (ia < e1) ? __expf(q1) : 0.f;
        float w2 = (ia + 1 < e1) ? __expf(q2) : 0.f;
        s += w1 + w2;
        h2 w1h = h2{(half_t)w1, (half_t)w1};
        h2 w2h = h2{(half_t)w2, (half_t)w2};
#pragma unroll
        for (int j = 0; j < 4; ++j)
            acc2[j] += w1h * xvA[j] + w2h * xvB[j];
        ia += PER;
    }
    if constexpr (GROUPS == 2) {
        s += __shfl_xor(s, 32, 64);
#pragma unroll
        for (int j = 0; j < 4; ++j) {
            float tmp = __builtin_bit_cast(float, acc2[j]);
            float o = __shfl_xor(tmp, 32, 64);
            acc2[j] += __builtin_bit_cast(h2, o);
        }
    }
    float r = 1.f / (s + 1e-16f);
    if (GROUPS == 1 || gid == 0) {
        half_t t[8];
#pragma unroll
        for (int j = 0; j < 4; ++j) {
#pragma unroll
            for (int p = 0; p < 2; ++p) {
                int c = cbase + 2 * j + p;
                float val = (float)acc2[j][p] * r + bias[c];
                float y = bng[c] * (val - bnm[c]) * rsqrtf(bnv[c] + 1e-5f) + bnb[c];
                t[2 * j + p] = (half_t)fmaxf(y, 0.f);
            }
        }
        uint4 qo;
        qo.x = u_bc(h2{t[0], t[1]});
        qo.y = u_bc(h2{t[2], t[3]});
        qo.z = u_bc(h2{t[4], t[5]});
        qo.w = u_bc(h2{t[6], t[7]});
        *(uint4*)(out_ + (size_t)node * TOT + cbase) = qo;
    }
}

// ---------------- gat2: r8 loop shape, fp16, ring-2 prefetch ----------------
template <int O>
__global__ __launch_bounds__(256, 4) void gat2_kernel(
    const half_t* __restrict__ xl_, const half_t* __restrict__ xr_,
    int stride,
    const int* __restrict__ rowptr, const int* __restrict__ col,
    const float* __restrict__ att, const float* __restrict__ bias,
    const float* __restrict__ bng, const float* __restrict__ bnb,
    const float* __restrict__ bnm, const float* __restrict__ bnv,
    half_t* __restrict__ out_) {
    constexpr int VE = O / 16;        // 8
    constexpr int HO = 4 * O;
    const int wave = threadIdx.x >> 6;
    const int node = blockIdx.x * 4 + wave;
    if (node >= N_NODES) return;
    const int lane = threadIdx.x & 63;
    const int l16 = lane & 15;
    const int cbase = (lane >> 4) * O + l16 * VE;

    h2 xr2[4], a06[4], a04[4], acc2[4], xvA[4], xvB[4];
    {
        uint4 q = *(const uint4*)(xr_ + (size_t)node * stride + cbase);
        xr2[0] = h2_bc(q.x); xr2[1] = h2_bc(q.y);
        xr2[2] = h2_bc(q.z); xr2[3] = h2_bc(q.w);
#pragma unroll
        for (int v = 0; v < VE; v += 4) {
            float4 b = *(const float4*)(att + cbase + v);
            a06[v / 2]     = h2{(half_t)(0.6f * b.x), (half_t)(0.6f * b.y)};
            a06[v / 2 + 1] = h2{(half_t)(0.6f * b.z), (half_t)(0.6f * b.w)};
            a04[v / 2]     = h2{(half_t)(0.4f * b.x), (half_t)(0.4f * b.y)};
            a04[v / 2 + 1] = h2{(half_t)(0.4f * b.z), (half_t)(0.4f * b.w)};
        }
    }
    float s;
    {
        unsigned ws_[4];
        *(uint4*)ws_ = *(const uint4*)(xl_ + (size_t)node * stride + cbase);
        float q = edge_logit_h(ws_, xr2, a06, a04, xvA);
#pragma unroll
        for (int d = 1; d < 16; d <<= 1) q += __shfl_xor(q, d, 64);
        float w0 = __expf(q);
        s = w0;
        h2 w0h = h2{(half_t)w0, (half_t)w0};
#pragma unroll
        for (int j = 0; j < 4; ++j) acc2[j] = w0h * xvA[j];
    }

    int e = rowptr[node];
    const int e1 = rowptr[node + 1];
    const int elast = e1 - 1;
    unsigned nA[4], nB[4], mA[4], mB[4];
    if (e < e1) *(uint4*)nA = *(const uint4*)(xl_ + (size_t)col[e] * stride + cbase);
    if (e + 1 < e1) *(uint4*)nB = *(const uint4*)(xl_ + (size_t)col[e + 1] * stride + cbase);
    if (e + 2 < e1) *(uint4*)mA = *(const uint4*)(xl_ + (size_t)col[e + 2] * stride + cbase);
    if (e + 3 < e1) *(uint4*)mB = *(const uint4*)(xl_ + (size_t)col[e + 3] * stride + cbase);
    while (e + 1 < e1) {
        unsigned cA[4], cB[4];
#pragma unroll
        for (int i = 0; i < 4; ++i) {
            cA[i] = nA[i]; cB[i] = nB[i];
            nA[i] = mA[i]; nB[i] = mB[i];
        }
        int i4 = e + 4 < elast ? e + 4 : elast;   // ring-2: prefetch pair at e+4
        int i5 = e + 5 < elast ? e + 5 : elast;
        *(uint4*)mA = *(const uint4*)(xl_ + (size_t)col[i4] * stride + cbase);
        *(uint4*)mB = *(const uint4*)(xl_ + (size_t)col[i5] * stride + cbase);
        e += 2;
        float q1 = edge_logit_h(cA, xr2, a06, a04, xvA);
        float q2 = edge_logit_h(cB, xr2, a06, a04, xvB);
#pragma unroll
        for (int d = 1; d < 16; d <<= 1) {
            q1 += __shfl_xor(q1, d, 64);
            q2 += __shfl_xor(q2, d, 64);
        }
        float w1 = __expf(q1), w2 = __expf(q2);
        s += w1 + w2;
        h2 w1h = h2{(half_t)w1, (half_t)w1};
        h2 w2h = h2{(half_t)w2, (half_t)w2};
#pragma unroll
        for (int j = 0; j < 4; ++j)
            acc2[j] += w1h * xvA[j] + w2h * xvB[j];
    }
    if (e < e1) {   // odd tail (row already in nA after shifts)
        float q = edge_logit_h(nA, xr2, a06, a04, xvA);
#pragma unroll
        for (int d = 1; d < 16; d <<= 1) q += __shfl_xor(q, d, 64);
        float we = __expf(q);
        s += we;
        h2 weh = h2{(half_t)we, (half_t)we};
#pragma unroll
        for (int j = 0; j < 4; ++j) acc2[j] += weh * xvA[j];
    }
    float r = 1.f / (s + 1e-16f);
    half_t t[8];
#pragma unroll
    for (int j = 0; j < 4; ++j) {
#pragma unroll
        for (int p = 0; p < 2; ++p) {
            int c = cbase + 2 * j + p;
            float val = (float)acc2[j][p] * r + bias[c];
            float y = bng[c] * (val - bnm[c]) * rsqrtf(bnv[c] + 1e-5f) + bnb[c];
            t[2 * j + p] = (half_t)fmaxf(y, 0.f);
        }
    }
    uint4 qo;
    qo.x = u_bc(h2{t[0], t[1]});
    qo.y = u_bc(h2{t[2], t[3]});
    qo.z = u_bc(h2{t[4], t[5]});
    qo.w = u_bc(h2{t[6], t[7]});
    *(uint4*)(out_ + (size_t)node * HO + cbase) = qo;
}

// ---------------- mean pool: 4 blocks/graph x 4 row-stripes (high TLP) ----------------
__global__ __launch_bounds__(256) void pool_kernel(const half_t* __restrict__ hb,
                                                   const int* __restrict__ gs,
                                                   float* __restrict__ pooled) {
    __shared__ float red[4][128];
    const int g = blockIdx.x >> 2;
    const int q = blockIdx.x & 3;
    const int t = threadIdx.x;
    const int p = t >> 6, w = t & 63;
    const int s = gs[g], e = gs[g + 1];
    const half_t* base = hb + q * 128 + w * 2;
    float a0 = 0.f, a1 = 0.f;
    for (int r = s + p; r < e; r += 4) {
        unsigned u = *(const unsigned*)(base + (size_t)r * HO2);
        h2 v = h2_bc(u);
        a0 += (float)v[0];
        a1 += (float)v[1];
    }
    red[p][w * 2] = a0;
    red[p][w * 2 + 1] = a1;
    __syncthreads();
    if (p == 0) {
        float inv = 1.f / fmaxf((float)(e - s), 1.f);
        float v0 = (red[0][w * 2] + red[1][w * 2] + red[2][w * 2] + red[3][w * 2]) * inv;
        float v1 = (red[0][w * 2 + 1] + red[1][w * 2 + 1] + red[2][w * 2 + 1] + red[3][w * 2 + 1]) * inv;
        float2 o; o.x = v0; o.y = v1;
        *(float2*)(pooled + (size_t)g * HO2 + q * 128 + w * 2) = o;
    }
}

// ---------------- MLP head ----------------
__global__ __launch_bounds__(128) void mlp_kernel(const float* __restrict__ pooled,
                                                  const float* __restrict__ gf,
                                                  const float* __restrict__ fc1w,
                                                  const float* __restrict__ fc1b,
                                                  const float* __restrict__ fc2w,
                                                  const float* __restrict__ fc2b,
                                                  float* __restrict__ out) {
    __shared__ float z[704];
    __shared__ float red[2];
    const int g = blockIdx.x, t = threadIdx.x;
    for (int i = t; i < HO2; i += 128) z[i] = pooled[(size_t)g * HO2 + i];
    for (int i = t; i < GF_DIM; i += 128) z[HO2 + i] = gf[(size_t)g * GF_DIM + i];
    __syncthreads();
    float s = fc1b[t];
    for (int k = 0; k < Z_DIM; ++k) s += z[k] * fc1w[k * FC1_DIM + t];
    s = fmaxf(s, 0.f);              // relu (dropout = identity in eval)
    float c = s * fc2w[t];
#pragma unroll
    for (int d = 1; d < 64; d <<= 1) c += __shfl_xor(c, d, 64);
    if ((t & 63) == 0) red[t >> 6] = c;
    __syncthreads();
    if (t == 0) out[g] = red[0] + red[1] + fc2b[0];
}

// ---------------- launch ----------------
extern "C" void kernel_launch(void* const* d_in, const int* in_sizes, int n_in,
                              void* d_out, int out_size, void* d_ws, size_t ws_size,
                              hipStream_t stream) {
    float* out = (float*)d_out;
    if (ws_size < WS_REQUIRED) {
        diag_kernel<<<1, 256, 0, stream>>>(out, (float)(ws_size >> 20));
        return;
    }
    const float* x     = (const float*)d_in[0];
    const int*   ei    = (const int*)d_in[1];
    const int*   batch = (const int*)d_in[2];
    const float* gf    = (const float*)d_in[3];
    const float* Wl1   = (const float*)d_in[4];
    const float* bl1   = (const float*)d_in[5];
    const float* Wr1   = (const float*)d_in[6];
    const float* br1   = (const float*)d_in[7];
    const float* att1  = (const float*)d_in[8];
    const float* bias1 = (const float*)d_in[9];
    const float* bn1g  = (const float*)d_in[10];
    const float* bn1b  = (const float*)d_in[11];
    const float* bn1m  = (const float*)d_in[12];
    const float* bn1v  = (const float*)d_in[13];
    const float* Wl2   = (const float*)d_in[14];
    const float* bl2   = (const float*)d_in[15];
    const float* Wr2   = (const float*)d_in[16];
    const float* br2   = (const float*)d_in[17];
    const float* att2  = (const float*)d_in[18];
    const float* bias2 = (const float*)d_in[19];
    const float* bn2g  = (const float*)d_in[20];
    const float* bn2b  = (const float*)d_in[21];
    const float* bn2m  = (const float*)d_in[22];
    const float* bn2v  = (const float*)d_in[23];
    const float* fc1w  = (const float*)d_in[24];
    const float* fc1b  = (const float*)d_in[25];
    const float* fc2w  = (const float*)d_in[26];
    const float* fc2b  = (const float*)d_in[27];
    char* ws = (char*)d_ws;

    half_t* xl1  = (half_t*)(ws + OFF_XL1);
    half_t* xr1  = (half_t*)(ws + OFF_XR1);
    half_t* xlr2 = (half_t*)(ws + OFF_XLR2);
    half_t* h1   = (half_t*)(ws + OFF_H1);
    half_t* h2b  = (half_t*)(ws + OFF_H2);
    int* deg     = (int*)(ws + OFF_DEG);
    int* rowptr  = (int*)(ws + OFF_ROWPTR);
    int* cursor  = (int*)(ws + OFF_CURSOR);
    int* col     = (int*)(ws + OFF_COL);
    int* gs      = (int*)(ws + OFF_GS);
    float* pooled= (float*)(ws + OFF_POOLED);
    half_t* Wt   = (half_t*)(ws + OFF_WCAT);
    float* bcat  = (float*)(ws + OFF_BCAT);

    // setup (zero deg | gstart | pack W2) -> [mm1 || count] -> scan -> fill
    setup_kernel<<<1221, 256, 0, stream>>>(deg, batch, gs, Wl2, Wr2, bl2, br2, Wt, bcat);
    mm1_count_kernel<<<N_NODES / 8 + N_EDGES / 256, 256, 0, stream>>>(
        x, Wl1, bl1, Wr1, br1, xl1, xr1, ei, deg);
    scan_kernel<<<1, 1024, 0, stream>>>(deg, rowptr, cursor);
    fill_kernel<<<(N_EDGES + 255) / 256, 256, 0, stream>>>(ei, cursor, col);

    // layer 1 gather (fp16, 4 edges/wave, ring-2 prefetch)
    gat_node_kernel<64, 2><<<(N_NODES + 3) / 4, 256, 0, stream>>>(
        xl1, xr1, HO1, rowptr, col, att1, bias1, bn1g, bn1b, bn1m, bn1v, h1);

    // layer 2 (f16 MFMA GEMM, direct-to-LDS dbuf + ring-2 gat2)
    mm2_mfma_kernel<<<dim3(8, (N_NODES + 127) / 128), 256, 0, stream>>>(h1, Wt, bcat, xlr2);
    gat2_kernel<128><<<(N_NODES + 3) / 4, 256, 0, stream>>>(
        xlr2, xlr2 + HO2, 1024, rowptr, col, att2, bias2, bn2g, bn2b, bn2m, bn2v, h2b);

    // pool + head
    pool_kernel<<<N_GRAPHS * 4, 256, 0, stream>>>(h2b, gs, pooled);
    mlp_kernel<<<N_GRAPHS, 128, 0, stream>>>(pooled, gf, fc1w, fc1b, fc2w, fc2b, out);
}

// Round 18
// 574.910 us; speedup vs baseline: 1.3016x; 1.0093x over previous
//
#include <hip/hip_runtime.h>

#define N_NODES 50000
#define N_EDGES 800000
#define N_GRAPHS 256
#define F_IN 9
#define GF_DIM 187
#define HO1 256
#define HO2 512
#define FC1_DIM 128
#define Z_DIM (HO2 + GF_DIM)   // 699

// ---------------- workspace layout (bytes) — proven footprint ----------------
#define OFF_XL1   0UL
#define OFF_XR1   25600000UL
#define OFF_XLR2  0UL
#define OFF_H1    102400000UL
#define OFF_H2    102400000UL
#define OFF_SMALL 153600000UL
#define OFF_DEG    (OFF_SMALL + 0UL)
#define OFF_ROWPTR (OFF_SMALL + 200704UL)
#define OFF_CURSOR (OFF_SMALL + 401408UL)
#define OFF_COL    (OFF_SMALL + 602112UL)
#define OFF_GS     (OFF_SMALL + 3802112UL)
#define OFF_POOLED (OFF_SMALL + 3806208UL)   // 512 KB fp32 pooled
#define OFF_WCAT   (OFF_SMALL + 4330496UL)
#define OFF_BCAT   (OFF_SMALL + 5379072UL)
#define WS_REQUIRED (OFF_SMALL + 5383168UL)   // 158,983,168 (proven)

typedef _Float16 half_t;
typedef __attribute__((ext_vector_type(2))) _Float16 h2;
typedef __attribute__((ext_vector_type(8))) _Float16 half8;   // f16 MFMA frag
typedef __attribute__((ext_vector_type(4))) float floatx4;

__device__ __forceinline__ h2 h2_bc(unsigned u) { return __builtin_bit_cast(h2, u); }
__device__ __forceinline__ unsigned u_bc(h2 v) { return __builtin_bit_cast(unsigned, v); }

// async global->LDS, 16B per lane; LDS dest = wave-uniform base + lane*16
__device__ __forceinline__ void gl2lds16(const half_t* g, half_t* l) {
    __builtin_amdgcn_global_load_lds((const __attribute__((address_space(1))) void*)g,
                                     (__attribute__((address_space(3))) void*)l,
                                     16, 0, 0);
}

// packed logit step over 4 words (8 halves): q += a06.(xs+xr) + a04.|xs+xr|
__device__ __forceinline__ float edge_logit_h(const unsigned* w, const h2* xr2,
                                              const h2* a06, const h2* a04,
                                              h2* xv2) {
    float q = 0.f;
#pragma unroll
    for (int i = 0; i < 4; ++i) {
        h2 xs = h2_bc(w[i]);
        xv2[i] = xs;
        h2 v = xs + xr2[i];                       // v_pk_add_f16
        q = __builtin_amdgcn_fdot2(a06[i], v, q, false);
        h2 va = h2_bc(u_bc(v) & 0x7fff7fffu);     // packed abs
        q = __builtin_amdgcn_fdot2(a04[i], va, q, false);
    }
    return q;
}

// ---------------- diagnostic fallback (ws too small) ----------------
__global__ void diag_kernel(float* out, float v) { out[threadIdx.x] = v; }

// ---------------- zero deg (must precede count) ----------------
__global__ __launch_bounds__(256) void zero_deg_kernel(int* __restrict__ deg) {
    int i = blockIdx.x * 256 + threadIdx.x;
    if (i < N_NODES) deg[i] = 0;
}

// ---------------- mega: mm1 | count | gstart | packW2 (all independent) ----------------
// blocks [0,6249]: mm1 (8 nodes/blk); [6250,9374]: count; 9375: gstart;
// [9376,10399]: pack Wl2|Wr2 -> Wt fp16 [1024 n][256 k] + bcat.
__global__ __launch_bounds__(256) void mega_kernel(const float* __restrict__ x,
                                                   const float* __restrict__ Wl,
                                                   const float* __restrict__ bl,
                                                   const float* __restrict__ Wr,
                                                   const float* __restrict__ br,
                                                   half_t* __restrict__ xl,
                                                   half_t* __restrict__ xr,
                                                   const int* __restrict__ ei,
                                                   int* __restrict__ deg,
                                                   const int* __restrict__ batch,
                                                   int* __restrict__ gs,
                                                   const float* __restrict__ Wl2,
                                                   const float* __restrict__ Wr2,
                                                   const float* __restrict__ bl2,
                                                   const float* __restrict__ br2,
                                                   half_t* __restrict__ Wt,
                                                   float* __restrict__ bcat) {
    __shared__ float xs[8][F_IN];
    const int b = blockIdx.x, t = threadIdx.x;
    if (b >= 9376) {                  // packW2 branch (1024 blocks)
        int i = (b - 9376) * 256 + t; // 0 .. 1024*256-1
        int n = i >> 8, k = i & 255;
        float w = (n < HO2) ? Wl2[k * HO2 + n] : Wr2[k * HO2 + (n - HO2)];
        Wt[i] = (half_t)w;
        if (i < 1024) bcat[i] = (i < HO2) ? bl2[i] : br2[i - HO2];
        return;
    }
    if (b == 9375) {                  // gstart branch (batch sorted; t = graph id)
        int lo = 0, hi = N_NODES;
        while (lo < hi) {
            int mid = (lo + hi) >> 1;
            if (batch[mid] < t) lo = mid + 1; else hi = mid;
        }
        gs[t] = lo;
        if (t == 0) gs[N_GRAPHS] = N_NODES;
        return;
    }
    if (b >= N_NODES / 8) {           // count branch (3125 blocks)
        int e = (b - N_NODES / 8) * 256 + t;
        if (e < N_EDGES) atomicAdd(&deg[ei[N_EDGES + e]], 1);
        return;
    }
    const int n0 = b * 8;             // mm1 branch
    if (t < 8 * F_IN) xs[t / F_IN][t % F_IN] = x[n0 * F_IN + t];
    __syncthreads();
    const float blv = bl[t], brv = br[t];
    float sl[8], sr[8];
#pragma unroll
    for (int i = 0; i < 8; ++i) { sl[i] = blv; sr[i] = brv; }
#pragma unroll
    for (int k = 0; k < F_IN; ++k) {
        float wlk = Wl[k * HO1 + t];
        float wrk = Wr[k * HO1 + t];
#pragma unroll
        for (int i = 0; i < 8; ++i) {
            sl[i] = fmaf(xs[i][k], wlk, sl[i]);
            sr[i] = fmaf(xs[i][k], wrk, sr[i]);
        }
    }
#pragma unroll
    for (int i = 0; i < 8; ++i) {
        xl[(size_t)(n0 + i) * HO1 + t] = (half_t)sl[i];
        xr[(size_t)(n0 + i) * HO1 + t] = (half_t)sr[i];
    }
}

// ---------------- CSR scan (vectorized int4 loads/stores, 52 elems/thread) ----------------
__global__ __launch_bounds__(1024) void scan_kernel(const int* __restrict__ deg,
                                                    int* __restrict__ rowptr,
                                                    int* __restrict__ cursor) {
    __shared__ int part[1024];
    const int t = threadIdx.x;
    const int lo = t * 52;            // 16B-aligned chunks; 52*1024 = 53248 > N_NODES
    int d[52];
    int s = 0;
#pragma unroll
    for (int i = 0; i < 13; ++i) {    // overread past N_NODES stays inside ws; masked
        int4 v = *(const int4*)(deg + lo + 4 * i);
        int i0 = lo + 4 * i;
        d[4 * i + 0] = (i0 + 0 < N_NODES) ? v.x : 0;
        d[4 * i + 1] = (i0 + 1 < N_NODES) ? v.y : 0;
        d[4 * i + 2] = (i0 + 2 < N_NODES) ? v.z : 0;
        d[4 * i + 3] = (i0 + 3 < N_NODES) ? v.w : 0;
        s += d[4 * i] + d[4 * i + 1] + d[4 * i + 2] + d[4 * i + 3];
    }
    part[t] = s;
    __syncthreads();
    for (int off = 1; off < 1024; off <<= 1) {
        int v = (t >= off) ? part[t - off] : 0;
        __syncthreads();
        part[t] += v;
        __syncthreads();
    }
    int run = part[t] - s;  // exclusive base
#pragma unroll
    for (int i = 0; i < 13; ++i) {
        int i0 = lo + 4 * i;
        int4 r;
        r.x = run; run += d[4 * i + 0];
        r.y = run; run += d[4 * i + 1];
        r.z = run; run += d[4 * i + 2];
        r.w = run; run += d[4 * i + 3];
        if (i0 + 3 < N_NODES) {           // full vector in-bounds
            *(int4*)(rowptr + i0) = r;
            *(int4*)(cursor + i0) = r;
        } else {                          // masked scalar tail
            int rr[4] = {r.x, r.y, r.z, r.w};
#pragma unroll
            for (int j = 0; j < 4; ++j)
                if (i0 + j < N_NODES) { rowptr[i0 + j] = rr[j]; cursor[i0 + j] = rr[j]; }
        }
    }
    if (t == 1023) rowptr[N_NODES] = part[1023];
}

__global__ __launch_bounds__(256) void fill_kernel(const int* __restrict__ ei,
                                                   int* __restrict__ cursor,
                                                   int* __restrict__ col) {
    int e = blockIdx.x * 256 + threadIdx.x;
    if (e < N_EDGES) {
        int d = ei[N_EDGES + e];
        int pos = atomicAdd(&cursor[d], 1);
        col[pos] = ei[e];
    }
}

// ---------------- layer-2 linear: f16 MFMA, direct-to-LDS double-buffered ----------------
__global__ __launch_bounds__(256) void mm2_mfma_kernel(
    const half_t* __restrict__ A,    // h1 fp16 [N,256]
    const half_t* __restrict__ Bt,   // Wt fp16 [1024][256]
    const float* __restrict__ bias,  // bcat [1024]
    half_t* __restrict__ C) {        // xlr2 fp16 [N,1024]
    __shared__ half_t As[2][128 * 32];  // 2 x 8 KB
    __shared__ half_t Bs[2][128 * 32];  // 2 x 8 KB
    const int t = threadIdx.x;
    const int lane = t & 63;
    const int w = t >> 6;
    const int wr = w >> 1, wc = w & 1;       // wave quadrant (64x64)
    const int l15 = lane & 15, kq = lane >> 4;
    const int row0 = blockIdx.y * 128;
    const int col0 = blockIdx.x * 128;

    const int c1 = t, c2 = t + 256;
    int ar1 = row0 + (c1 >> 2); ar1 = ar1 < N_NODES ? ar1 : N_NODES - 1;
    int ar2 = row0 + (c2 >> 2); ar2 = ar2 < N_NODES ? ar2 : N_NODES - 1;
    const half_t* pa1 = A + (size_t)ar1 * 256 + (c1 & 3) * 8;
    const half_t* pa2 = A + (size_t)ar2 * 256 + (c2 & 3) * 8;
    const half_t* pb1 = Bt + (size_t)(col0 + (c1 >> 2)) * 256 + (c1 & 3) * 8;
    const half_t* pb2 = Bt + (size_t)(col0 + (c2 >> 2)) * 256 + (c2 & 3) * 8;
    const int l1 = c1 * 8;      // halves: byte offset t*16
    const int l2 = c2 * 8;

    gl2lds16(pa1, &As[0][l1]);
    gl2lds16(pa2, &As[0][l2]);
    gl2lds16(pb1, &Bs[0][l1]);
    gl2lds16(pb2, &Bs[0][l2]);

    floatx4 acc[4][4] = {};
    int buf = 0;
    for (int k0 = 0; k0 < 256; k0 += 32) {
        __syncthreads();             // drains vmcnt: LDS[buf] ready
        const bool more = (k0 + 32 < 256);
        if (more) {
            int nb = 1 - buf;
            gl2lds16(pa1 + k0 + 32, &As[nb][l1]);
            gl2lds16(pa2 + k0 + 32, &As[nb][l2]);
            gl2lds16(pb1 + k0 + 32, &Bs[nb][l1]);
            gl2lds16(pb2 + k0 + 32, &Bs[nb][l2]);
        }
        half8 af[4], bf[4];
#pragma unroll
        for (int i = 0; i < 4; ++i)
            af[i] = *(const half8*)&As[buf][(wr * 64 + i * 16 + l15) * 32 + kq * 8];
#pragma unroll
        for (int j = 0; j < 4; ++j)
            bf[j] = *(const half8*)&Bs[buf][(wc * 64 + j * 16 + l15) * 32 + kq * 8];
#pragma unroll
        for (int i = 0; i < 4; ++i)
#pragma unroll
            for (int j = 0; j < 4; ++j)
                acc[i][j] = __builtin_amdgcn_mfma_f32_16x16x32_f16(
                    af[i], bf[j], acc[i][j], 0, 0, 0);
        if (more) buf = 1 - buf;
    }
#pragma unroll
    for (int j = 0; j < 4; ++j) {
        int col = col0 + wc * 64 + j * 16 + l15;
        float bj = bias[col];
#pragma unroll
        for (int i = 0; i < 4; ++i) {
            int rbase = row0 + wr * 64 + i * 16 + kq * 4;
            floatx4 v = acc[i][j];
#pragma unroll
            for (int r = 0; r < 4; ++r) {
                int row = rbase + r;
                if (row < N_NODES) C[(size_t)row * 1024 + col] = (half_t)(v[r] + bj);
            }
        }
    }
}

// ---------------- gat1: GROUPS=2 lane-split, fp16, distance-1 prefetch (r16 proven) ----------------
template <int O, int GROUPS>
__global__ __launch_bounds__(256, 4) void gat_node_kernel(
    const half_t* __restrict__ xl_, const half_t* __restrict__ xr_,
    int stride,
    const int* __restrict__ rowptr, const int* __restrict__ col,
    const float* __restrict__ att, const float* __restrict__ bias,
    const float* __restrict__ bng, const float* __restrict__ bnb,
    const float* __restrict__ bnm, const float* __restrict__ bnv,
    half_t* __restrict__ out_) {
    constexpr int TOT = 4 * O;
    constexpr int GS  = 64 / GROUPS;
    constexpr int VE  = TOT / GS;     // 8
    constexpr int LPH = O / VE;
    const int wave = threadIdx.x >> 6;
    const int node = blockIdx.x * 4 + wave;
    if (node >= N_NODES) return;
    const int lane = threadIdx.x & 63;
    const int gid  = lane / GS;
    const int gl   = lane % GS;
    const int cbase = gl * VE;

    h2 xr2[4], a06[4], a04[4], acc2[4], xvA[4], xvB[4];
    {
        uint4 q = *(const uint4*)(xr_ + (size_t)node * stride + cbase);
        xr2[0] = h2_bc(q.x); xr2[1] = h2_bc(q.y);
        xr2[2] = h2_bc(q.z); xr2[3] = h2_bc(q.w);
#pragma unroll
        for (int v = 0; v < VE; v += 4) {
            float4 b = *(const float4*)(att + cbase + v);
            a06[v / 2]     = h2{(half_t)(0.6f * b.x), (half_t)(0.6f * b.y)};
            a06[v / 2 + 1] = h2{(half_t)(0.6f * b.z), (half_t)(0.6f * b.w)};
            a04[v / 2]     = h2{(half_t)(0.4f * b.x), (half_t)(0.4f * b.y)};
            a04[v / 2 + 1] = h2{(half_t)(0.4f * b.z), (half_t)(0.4f * b.w)};
        }
    }
    float s;
    {
        unsigned w_[4];
        *(uint4*)w_ = *(const uint4*)(xl_ + (size_t)node * stride + cbase);
        float q = edge_logit_h(w_, xr2, a06, a04, xvA);
#pragma unroll
        for (int d = 1; d < LPH; d <<= 1) q += __shfl_xor(q, d, 64);
        float w0 = (GROUPS == 1 || gid == 0) ? __expf(q) : 0.f;
        s = w0;
        h2 w0h = h2{(half_t)w0, (half_t)w0};
#pragma unroll
        for (int j = 0; j < 4; ++j) acc2[j] = w0h * xvA[j];
    }

    const int e0 = rowptr[node], e1 = rowptr[node + 1];
    const int deg = e1 - e0;
    constexpr int PER = 2 * GROUPS;
    const int itc = (deg + PER - 1) / PER;
    const int elast = e1 - 1;
    int ia = e0 + 2 * gid;
    unsigned nA[4], nB[4];
    if (itc > 0) {
        int a = ia < elast ? ia : elast;
        int b = ia + 1 < elast ? ia + 1 : elast;
        *(uint4*)nA = *(const uint4*)(xl_ + (size_t)col[a] * stride + cbase);
        *(uint4*)nB = *(const uint4*)(xl_ + (size_t)col[b] * stride + cbase);
    }
    for (int k = 0; k < itc; ++k) {
        unsigned cA[4], cB[4];
#pragma unroll
        for (int i = 0; i < 4; ++i) { cA[i] = nA[i]; cB[i] = nB[i]; }
        int inext = ia + PER;
        if (k + 1 < itc) {
            int a = inext < elast ? inext : elast;
            int b = inext + 1 < elast ? inext + 1 : elast;
            *(uint4*)nA = *(const uint4*)(xl_ + (size_t)col[a] * stride + cbase);
            *(uint4*)nB = *(const uint4*)(xl_ + (size_t)col[b] * stride + cbase);
        }
        float q1 = edge_logit_h(cA, xr2, a06, a04, xvA);
        float q2 = edge_logit_h(cB, xr2, a06, a04, xvB);
#pragma unroll
        for (int d = 1; d < LPH; d <<= 1) {
            q1 += __shfl_xor(q1, d, 64);
            q2 += __shfl_xor(q2, d, 64);
        }
        float w1 = (ia < e1) ? __expf(q1) : 0.f;
        float w2 = (ia + 1 < e1) ? __expf(q2) : 0.f;
        s += w1 + w2;
        h2 w1h = h2{(half_t)w1, (half_t)w1};
        h2 w2h = h2{(half_t)w2, (half_t)w2};
#pragma unroll
        for (int j = 0; j < 4; ++j)
            acc2[j] += w1h * xvA[j] + w2h * xvB[j];
        ia = inext;
    }
    if constexpr (GROUPS == 2) {
        s += __shfl_xor(s, 32, 64);
#pragma unroll
        for (int j = 0; j < 4; ++j) {
            float tmp = __builtin_bit_cast(float, acc2[j]);
            float o = __shfl_xor(tmp, 32, 64);
            acc2[j] += __builtin_bit_cast(h2, o);
        }
    }
    float r = 1.f / (s + 1e-16f);
    if (GROUPS == 1 || gid == 0) {
        half_t t[8];
#pragma unroll
        for (int j = 0; j < 4; ++j) {
#pragma unroll
            for (int p = 0; p < 2; ++p) {
                int c = cbase + 2 * j + p;
                float val = (float)acc2[j][p] * r + bias[c];
                float y = bng[c] * (val - bnm[c]) * rsqrtf(bnv[c] + 1e-5f) + bnb[c];
                t[2 * j + p] = (half_t)fmaxf(y, 0.f);
            }
        }
        uint4 qo;
        qo.x = u_bc(h2{t[0], t[1]});
        qo.y = u_bc(h2{t[2], t[3]});
        qo.z = u_bc(h2{t[4], t[5]});
        qo.w = u_bc(h2{t[6], t[7]});
        *(uint4*)(out_ + (size_t)node * TOT + cbase) = qo;
    }
}

// ---------------- gat2: r8 loop shape, fp16, distance-1 prefetch (r16 proven) ----------------
template <int O>
__global__ __launch_bounds__(256, 4) void gat2_kernel(
    const half_t* __restrict__ xl_, const half_t* __restrict__ xr_,
    int stride,
    const int* __restrict__ rowptr, const int* __restrict__ col,
    const float* __restrict__ att, const float* __restrict__ bias,
    const float* __restrict__ bng, const float* __restrict__ bnb,
    const float* __restrict__ bnm, const float* __restrict__ bnv,
    half_t* __restrict__ out_) {
    constexpr int VE = O / 16;        // 8
    constexpr int HO = 4 * O;
    const int wave = threadIdx.x >> 6;
    const int node = blockIdx.x * 4 + wave;
    if (node >= N_NODES) return;
    const int lane = threadIdx.x & 63;
    const int l16 = lane & 15;
    const int cbase = (lane >> 4) * O + l16 * VE;

    h2 xr2[4], a06[4], a04[4], acc2[4], xvA[4], xvB[4];
    {
        uint4 q = *(const uint4*)(xr_ + (size_t)node * stride + cbase);
        xr2[0] = h2_bc(q.x); xr2[1] = h2_bc(q.y);
        xr2[2] = h2_bc(q.z); xr2[3] = h2_bc(q.w);
#pragma unroll
        for (int v = 0; v < VE; v += 4) {
            float4 b = *(const float4*)(att + cbase + v);
            a06[v / 2]     = h2{(half_t)(0.6f * b.x), (half_t)(0.6f * b.y)};
            a06[v / 2 + 1] = h2{(half_t)(0.6f * b.z), (half_t)(0.6f * b.w)};
            a04[v / 2]     = h2{(half_t)(0.4f * b.x), (half_t)(0.4f * b.y)};
            a04[v / 2 + 1] = h2{(half_t)(0.4f * b.z), (half_t)(0.4f * b.w)};
        }
    }
    float s;
    {
        unsigned ws_[4];
        *(uint4*)ws_ = *(const uint4*)(xl_ + (size_t)node * stride + cbase);
        float q = edge_logit_h(ws_, xr2, a06, a04, xvA);
#pragma unroll
        for (int d = 1; d < 16; d <<= 1) q += __shfl_xor(q, d, 64);
        float w0 = __expf(q);
        s = w0;
        h2 w0h = h2{(half_t)w0, (half_t)w0};
#pragma unroll
        for (int j = 0; j < 4; ++j) acc2[j] = w0h * xvA[j];
    }

    int e = rowptr[node];
    const int e1 = rowptr[node + 1];
    const int elast = e1 - 1;
    unsigned nA[4], nB[4];
    if (e < e1) *(uint4*)nA = *(const uint4*)(xl_ + (size_t)col[e] * stride + cbase);
    if (e + 1 < e1) *(uint4*)nB = *(const uint4*)(xl_ + (size_t)col[e + 1] * stride + cbase);
    while (e + 1 < e1) {
        unsigned cA[4], cB[4];
#pragma unroll
        for (int i = 0; i < 4; ++i) { cA[i] = nA[i]; cB[i] = nB[i]; }
        int i2 = e + 2 < elast ? e + 2 : elast;
        int i3 = e + 3 < elast ? e + 3 : elast;
        *(uint4*)nA = *(const uint4*)(xl_ + (size_t)col[i2] * stride + cbase);
        *(uint4*)nB = *(const uint4*)(xl_ + (size_t)col[i3] * stride + cbase);
        e += 2;
        float q1 = edge_logit_h(cA, xr2, a06, a04, xvA);
        float q2 = edge_logit_h(cB, xr2, a06, a04, xvB);
#pragma unroll
        for (int d = 1; d < 16; d <<= 1) {
            q1 += __shfl_xor(q1, d, 64);
            q2 += __shfl_xor(q2, d, 64);
        }
        float w1 = __expf(q1), w2 = __expf(q2);
        s += w1 + w2;
        h2 w1h = h2{(half_t)w1, (half_t)w1};
        h2 w2h = h2{(half_t)w2, (half_t)w2};
#pragma unroll
        for (int j = 0; j < 4; ++j)
            acc2[j] += w1h * xvA[j] + w2h * xvB[j];
    }
    if (e < e1) {
        float q = edge_logit_h(nA, xr2, a06, a04, xvA);
#pragma unroll
        for (int d = 1; d < 16; d <<= 1) q += __shfl_xor(q, d, 64);
        float we = __expf(q);
        s += we;
        h2 weh = h2{(half_t)we, (half_t)we};
#pragma unroll
        for (int j = 0; j < 4; ++j) acc2[j] += weh * xvA[j];
    }
    float r = 1.f / (s + 1e-16f);
    half_t t[8];
#pragma unroll
    for (int j = 0; j < 4; ++j) {
#pragma unroll
        for (int p = 0; p < 2; ++p) {
            int c = cbase + 2 * j + p;
            float val = (float)acc2[j][p] * r + bias[c];
            float y = bng[c] * (val - bnm[c]) * rsqrtf(bnv[c] + 1e-5f) + bnb[c];
            t[2 * j + p] = (half_t)fmaxf(y, 0.f);
        }
    }
    uint4 qo;
    qo.x = u_bc(h2{t[0], t[1]});
    qo.y = u_bc(h2{t[2], t[3]});
    qo.z = u_bc(h2{t[4], t[5]});
    qo.w = u_bc(h2{t[6], t[7]});
    *(uint4*)(out_ + (size_t)node * HO + cbase) = qo;
}

// ---------------- mean pool: 4 blocks/graph x 4 row-stripes (high TLP) ----------------
__global__ __launch_bounds__(256) void pool_kernel(const half_t* __restrict__ hb,
                                                   const int* __restrict__ gs,
                                                   float* __restrict__ pooled) {
    __shared__ float red[4][128];
    const int g = blockIdx.x >> 2;
    const int q = blockIdx.x & 3;
    const int t = threadIdx.x;
    const int p = t >> 6, w = t & 63;
    const int s = gs[g], e = gs[g + 1];
    const half_t* base = hb + q * 128 + w * 2;
    float a0 = 0.f, a1 = 0.f;
    for (int r = s + p; r < e; r += 4) {
        unsigned u = *(const unsigned*)(base + (size_t)r * HO2);
        h2 v = h2_bc(u);
        a0 += (float)v[0];
        a1 += (float)v[1];
    }
    red[p][w * 2] = a0;
    red[p][w * 2 + 1] = a1;
    __syncthreads();
    if (p == 0) {
        float inv = 1.f / fmaxf((float)(e - s), 1.f);
        float v0 = (red[0][w * 2] + red[1][w * 2] + red[2][w * 2] + red[3][w * 2]) * inv;
        float v1 = (red[0][w * 2 + 1] + red[1][w * 2 + 1] + red[2][w * 2 + 1] + red[3][w * 2 + 1]) * inv;
        float2 o; o.x = v0; o.y = v1;
        *(float2*)(pooled + (size_t)g * HO2 + q * 128 + w * 2) = o;
    }
}

// ---------------- MLP head ----------------
__global__ __launch_bounds__(128) void mlp_kernel(const float* __restrict__ pooled,
                                                  const float* __restrict__ gf,
                                                  const float* __restrict__ fc1w,
                                                  const float* __restrict__ fc1b,
                                                  const float* __restrict__ fc2w,
                                                  const float* __restrict__ fc2b,
                                                  float* __restrict__ out) {
    __shared__ float z[704];
    __shared__ float red[2];
    const int g = blockIdx.x, t = threadIdx.x;
    for (int i = t; i < HO2; i += 128) z[i] = pooled[(size_t)g * HO2 + i];
    for (int i = t; i < GF_DIM; i += 128) z[HO2 + i] = gf[(size_t)g * GF_DIM + i];
    __syncthreads();
    float s = fc1b[t];
    for (int k = 0; k < Z_DIM; ++k) s += z[k] * fc1w[k * FC1_DIM + t];
    s = fmaxf(s, 0.f);              // relu (dropout = identity in eval)
    float c = s * fc2w[t];
#pragma unroll
    for (int d = 1; d < 64; d <<= 1) c += __shfl_xor(c, d, 64);
    if ((t & 63) == 0) red[t >> 6] = c;
    __syncthreads();
    if (t == 0) out[g] = red[0] + red[1] + fc2b[0];
}

// ---------------- launch ----------------
extern "C" void kernel_launch(void* const* d_in, const int* in_sizes, int n_in,
                              void* d_out, int out_size, void* d_ws, size_t ws_size,
                              hipStream_t stream) {
    float* out = (float*)d_out;
    if (ws_size < WS_REQUIRED) {
        diag_kernel<<<1, 256, 0, stream>>>(out, (float)(ws_size >> 20));
        return;
    }
    const float* x     = (const float*)d_in[0];
    const int*   ei    = (const int*)d_in[1];
    const int*   batch = (const int*)d_in[2];
    const float* gf    = (const float*)d_in[3];
    const float* Wl1   = (const float*)d_in[4];
    const float* bl1   = (const float*)d_in[5];
    const float* Wr1   = (const float*)d_in[6];
    const float* br1   = (const float*)d_in[7];
    const float* att1  = (const float*)d_in[8];
    const float* bias1 = (const float*)d_in[9];
    const float* bn1g  = (const float*)d_in[10];
    const float* bn1b  = (const float*)d_in[11];
    const float* bn1m  = (const float*)d_in[12];
    const float* bn1v  = (const float*)d_in[13];
    const float* Wl2   = (const float*)d_in[14];
    const float* bl2   = (const float*)d_in[15];
    const float* Wr2   = (const float*)d_in[16];
    const float* br2   = (const float*)d_in[17];
    const float* att2  = (const float*)d_in[18];
    const float* bias2 = (const float*)d_in[19];
    const float* bn2g  = (const float*)d_in[20];
    const float* bn2b  = (const float*)d_in[21];
    const float* bn2m  = (const float*)d_in[22];
    const float* bn2v  = (const float*)d_in[23];
    const float* fc1w  = (const float*)d_in[24];
    const float* fc1b  = (const float*)d_in[25];
    const float* fc2w  = (const float*)d_in[26];
    const float* fc2b  = (const float*)d_in[27];
    char* ws = (char*)d_ws;

    half_t* xl1  = (half_t*)(ws + OFF_XL1);
    half_t* xr1  = (half_t*)(ws + OFF_XR1);
    half_t* xlr2 = (half_t*)(ws + OFF_XLR2);
    half_t* h1   = (half_t*)(ws + OFF_H1);
    half_t* h2b  = (half_t*)(ws + OFF_H2);
    int* deg     = (int*)(ws + OFF_DEG);
    int* rowptr  = (int*)(ws + OFF_ROWPTR);
    int* cursor  = (int*)(ws + OFF_CURSOR);
    int* col     = (int*)(ws + OFF_COL);
    int* gs      = (int*)(ws + OFF_GS);
    float* pooled= (float*)(ws + OFF_POOLED);
    half_t* Wt   = (half_t*)(ws + OFF_WCAT);
    float* bcat  = (float*)(ws + OFF_BCAT);

    // zero deg -> mega (mm1 | count | gstart | packW2) -> scan -> fill
    zero_deg_kernel<<<196, 256, 0, stream>>>(deg);
    mega_kernel<<<10400, 256, 0, stream>>>(x, Wl1, bl1, Wr1, br1, xl1, xr1,
                                           ei, deg, batch, gs,
                                           Wl2, Wr2, bl2, br2, Wt, bcat);
    scan_kernel<<<1, 1024, 0, stream>>>(deg, rowptr, cursor);
    fill_kernel<<<(N_EDGES + 255) / 256, 256, 0, stream>>>(ei, cursor, col);

    // layer 1 gather (fp16, 4 edges/wave)
    gat_node_kernel<64, 2><<<(N_NODES + 3) / 4, 256, 0, stream>>>(
        xl1, xr1, HO1, rowptr, col, att1, bias1, bn1g, bn1b, bn1m, bn1v, h1);

    // layer 2 (f16 MFMA GEMM, direct-to-LDS dbuf + r16 gat2)
    mm2_mfma_kernel<<<dim3(8, (N_NODES + 127) / 128), 256, 0, stream>>>(h1, Wt, bcat, xlr2);
    gat2_kernel<128><<<(N_NODES + 3) / 4, 256, 0, stream>>>(
        xlr2, xlr2 + HO2, 1024, rowptr, col, att2, bias2, bn2g, bn2b, bn2m, bn2v, h2b);

    // pool + head
    pool_kernel<<<N_GRAPHS * 4, 256, 0, stream>>>(h2b, gs, pooled);
    mlp_kernel<<<N_GRAPHS, 128, 0, stream>>>(pooled, gf, fc1w, fc1b, fc2w, fc2b, out);
}